// Round 4
// baseline (719.454 us; speedup 1.0000x reference)
//
#include <hip/hip_runtime.h>
#include <math.h>

#define DT 0.1f
#define EPSL 1e-5f

// ---- output layout (float32, concatenated in reference return order) ----
#define XREC_OFF 0
#define QM_OFF   10035200
#define QV_OFF   10037248
#define ZT_OFF   10039296
#define LH_OFF   10141696
#define KL_OFF   10141697

// ---- workspace layout (bytes) ----
// lhp  float[3200]   @ 0
// klp  float[256]    @ 12800
// z0   float[2048]   @ 13824
// M1p  float[784*12] @ 22016
// Wc2  float[3200]   @ 59648
// Wc3  float[200]    @ 72448

// =====================================================================
// Prep: build M1p + parity-class repacked decoder weights.
// =====================================================================
__global__ __launch_bounds__(256) void prep_kernel(
    const float* __restrict__ fc3w, const float* __restrict__ fc3b,
    const float* __restrict__ dw1, const float* __restrict__ db1,
    const float* __restrict__ dw2, const float* __restrict__ dw3,
    float* __restrict__ M1p, float* __restrict__ Wc2, float* __restrict__ Wc3)
{
    int idx = blockIdx.x * 256 + threadIdx.x;
    if (idx < 9408) {                       // M1p [784][12]
        int m = idx / 12, j = idx % 12;
        float acc = 0.f;
        if (j < 9) {
            int oc = m / 49, r = m % 49, oy = r / 7, ox = r % 7;
            acc = (j == 8) ? db1[oc] : 0.f;
            for (int ky = 0; ky < 5; ++ky) {
                int ty = oy + ky - 2;
                if (ty < 0 || (ty & 1)) continue;
                int iy = ty >> 1; if (iy >= 4) continue;
                for (int kx = 0; kx < 5; ++kx) {
                    int tx = ox + kx - 2;
                    if (tx < 0 || (tx & 1)) continue;
                    int ix = tx >> 1; if (ix >= 4) continue;
                    for (int ic = 0; ic < 32; ++ic) {
                        float wv = dw1[((oc * 32 + ic) * 5 + ky) * 5 + kx];
                        int mi = ic * 16 + iy * 4 + ix;
                        acc += wv * ((j < 8) ? fc3w[mi * 8 + j] : fc3b[mi]);
                    }
                }
            }
        }
        M1p[idx] = acc;
    } else if (idx < 9408 + 3200) {         // Wc2 repack, dw2 [oc=8][ic=16][ky][kx]
        int iw = idx - 9408;
        int kx = iw % 5, t1 = iw / 5, ky = t1 % 5, t2 = t1 / 5, ic = t2 % 16, oc = t2 / 16;
        int cy = ky & 1, cx = kx & 1, dy = ky >> 1, dx = kx >> 1;
        int ny = cy ? 2 : 3, nx = cx ? 2 : 3, nt = ny * nx;
        const int off2[4] = {0, 1152, 1920, 2688};
        Wc2[off2[cy * 2 + cx] + (ic * 8 + oc) * nt + dy * nx + dx] = dw2[iw];
    } else if (idx < 9408 + 3200 + 200) {   // Wc3 repack
        int iw = idx - 12608;
        int kx = iw % 5, t1 = iw / 5, ky = t1 % 5, ic = t1 / 5;
        int cy = ky & 1, cx = kx & 1, dy = ky >> 1, dx = kx >> 1;
        int ny = cy ? 2 : 3, nx = cx ? 2 : 3, nt = ny * nx;
        const int off3[4] = {0, 72, 120, 168};
        Wc3[off3[cy * 2 + cx] + ic * nt + dy * nx + dx] = dw3[iw];
    }
}

// =====================================================================
// Encoder: one block per sample (unchanged).
// =====================================================================
__global__ __launch_bounds__(256) void enc_kernel(
    const float* __restrict__ X, const float* __restrict__ eps,
    const float* __restrict__ w1, const float* __restrict__ b1,
    const float* __restrict__ w2, const float* __restrict__ b2,
    const float* __restrict__ w3, const float* __restrict__ b3,
    const float* __restrict__ fc1w, const float* __restrict__ fc1b,
    const float* __restrict__ fc2w, const float* __restrict__ fc2b,
    float* __restrict__ out, float* __restrict__ z0, float* __restrict__ klp)
{
    __shared__ float img[784];
    __shared__ float a1[8 * 196];
    __shared__ float a2[16 * 49];
    __shared__ float h[512];
    __shared__ float kl_s[8];
    int n = blockIdx.x, tid = threadIdx.x;

    const float* xi = X + (size_t)n * 39200;
    for (int i = tid; i < 784; i += 256) img[i] = xi[i];
    __syncthreads();

    for (int idx = tid; idx < 1568; idx += 256) {
        int oc = idx / 196, r = idx % 196, oy = r / 14, ox = r % 14;
        float acc = b1[oc];
        for (int ky = 0; ky < 5; ++ky) {
            int iy = 2 * oy - 2 + ky; if (iy < 0 || iy >= 28) continue;
            for (int kx = 0; kx < 5; ++kx) {
                int ix = 2 * ox - 2 + kx; if (ix < 0 || ix >= 28) continue;
                acc += w1[oc * 25 + ky * 5 + kx] * img[iy * 28 + ix];
            }
        }
        a1[idx] = fmaxf(acc, 0.f);
    }
    __syncthreads();

    for (int idx = tid; idx < 784; idx += 256) {
        int oc = idx / 49, r = idx % 49, oy = r / 7, ox = r % 7;
        float acc = b2[oc];
        for (int ic = 0; ic < 8; ++ic)
            for (int ky = 0; ky < 5; ++ky) {
                int iy = 2 * oy - 2 + ky; if (iy < 0 || iy >= 14) continue;
                for (int kx = 0; kx < 5; ++kx) {
                    int ix = 2 * ox - 2 + kx; if (ix < 0 || ix >= 14) continue;
                    acc += w2[((oc * 8 + ic) * 5 + ky) * 5 + kx] * a1[ic * 196 + iy * 14 + ix];
                }
            }
        a2[idx] = fmaxf(acc, 0.f);
    }
    __syncthreads();

    for (int idx = tid; idx < 512; idx += 256) {
        int oc = idx / 16, r = idx % 16, oy = r / 4, ox = r % 4;
        float acc = b3[oc];
        for (int ic = 0; ic < 16; ++ic)
            for (int ky = 0; ky < 5; ++ky) {
                int iy = 2 * oy - 2 + ky; if (iy < 0 || iy >= 7) continue;
                for (int kx = 0; kx < 5; ++kx) {
                    int ix = 2 * ox - 2 + kx; if (ix < 0 || ix >= 7) continue;
                    acc += w3[((oc * 16 + ic) * 5 + ky) * 5 + kx] * a2[ic * 49 + iy * 7 + ix];
                }
            }
        h[idx] = fmaxf(acc, 0.f);
    }
    __syncthreads();

    if (tid < 8) {
        float m = fc1b[tid], lv = fc2b[tid];
        for (int k = 0; k < 512; ++k) {
            float hv = h[k];
            m  += fc1w[tid * 512 + k] * hv;
            lv += fc2w[tid * 512 + k] * hv;
        }
        float v = fmaxf(lv, 0.f) + log1pf(expf(-fabsf(lv)));
        float z = m + eps[n * 8 + tid] * v;
        out[QM_OFF + n * 8 + tid] = m;
        out[QV_OFF + n * 8 + tid] = v;
        z0[n * 8 + tid] = z;
        kl_s[tid] = -logf(v) + 0.5f * (v * v + m * m) - 0.5f;
    }
    __syncthreads();
    if (tid == 0) {
        float s = 0.f;
        for (int i = 0; i < 8; ++i) s += kl_s[i];
        klp[n] = s;
    }
}

// =====================================================================
// ODE v3 (unchanged): one wave per sample, register-resident weights.
// =====================================================================
__device__ __forceinline__ float rl(float v, int lane) {
    return __uint_as_float(__builtin_amdgcn_readlane(__float_as_uint(v), lane));
}
__device__ __forceinline__ float bcast(float lo, float hi, int k) {
    return (k < 64) ? rl(lo, k) : rl(hi, k - 64);
}

__global__ __launch_bounds__(64, 1) void ode_kernel(
    const float* __restrict__ z0,
    const float* __restrict__ fw1, const float* __restrict__ fb1,
    const float* __restrict__ fw2, const float* __restrict__ fb2,
    const float* __restrict__ fw3, const float* __restrict__ fb3,
    float* __restrict__ ztg)
{
    int n = blockIdx.x, L = threadIdx.x;
    bool hiv = (L < 36);
    int jA = L, jB = L + 64, i3 = L & 7;

    float w1x[8], w1y[8];
    float w2x[100], w2y[100], w3r[100];
    float b1A = fb1[jA], b1B = hiv ? fb1[jB] : 0.f;
    float b2A = fb2[jA], b2B = hiv ? fb2[jB] : 0.f;
    float b3r = fb3[i3];
    #pragma unroll
    for (int k = 0; k < 8; ++k) {
        w1x[k] = fw1[jA * 8 + k];
        w1y[k] = hiv ? fw1[jB * 8 + k] : 0.f;
    }
    #pragma unroll
    for (int k = 0; k < 100; ++k) {
        w2x[k] = fw2[jA * 100 + k];
        w2y[k] = hiv ? fw2[jB * 100 + k] : 0.f;
        w3r[k] = fw3[i3 * 100 + k];
    }

    float zc = z0[n * 8 + i3];
    if (L < 8) ztg[n * 400 + L] = zc;
    float vu[8];
    #pragma unroll
    for (int i = 0; i < 8; ++i) vu[i] = rl(zc, i);

    #pragma unroll 1
    for (int t = 1; t < 50; ++t) {
        float zsum = 0.f;
        #pragma unroll 1
        for (int st = 0; st < 4; ++st) {
            float aA = b1A, aB = b1B;
            #pragma unroll
            for (int k = 0; k < 8; ++k) {
                aA = fmaf(w1x[k], vu[k], aA);
                aB = fmaf(w1y[k], vu[k], aB);
            }
            aA = fmaxf(aA, 0.f); aB = fmaxf(aB, 0.f);

            float hA0 = b2A, hA1 = 0.f, hA2 = 0.f, hA3 = 0.f;
            float hB0 = b2B, hB1 = 0.f, hB2 = 0.f, hB3 = 0.f;
            #pragma unroll
            for (int k = 0; k < 100; k += 4) {
                float s0 = bcast(aA, aB, k + 0);
                float s1 = bcast(aA, aB, k + 1);
                float s2 = bcast(aA, aB, k + 2);
                float s3 = bcast(aA, aB, k + 3);
                hA0 = fmaf(w2x[k + 0], s0, hA0); hB0 = fmaf(w2y[k + 0], s0, hB0);
                hA1 = fmaf(w2x[k + 1], s1, hA1); hB1 = fmaf(w2y[k + 1], s1, hB1);
                hA2 = fmaf(w2x[k + 2], s2, hA2); hB2 = fmaf(w2y[k + 2], s2, hB2);
                hA3 = fmaf(w2x[k + 3], s3, hA3); hB3 = fmaf(w2y[k + 3], s3, hB3);
            }
            float hA = fmaxf((hA0 + hA1) + (hA2 + hA3), 0.f);
            float hB = fmaxf((hB0 + hB1) + (hB2 + hB3), 0.f);

            float o0 = b3r, o1 = 0.f, o2 = 0.f, o3 = 0.f;
            #pragma unroll
            for (int k = 0; k < 100; k += 4) {
                o0 = fmaf(w3r[k + 0], bcast(hA, hB, k + 0), o0);
                o1 = fmaf(w3r[k + 1], bcast(hA, hB, k + 1), o1);
                o2 = fmaf(w3r[k + 2], bcast(hA, hB, k + 2), o2);
                o3 = fmaf(w3r[k + 3], bcast(hA, hB, k + 3), o3);
            }
            float o = (o0 + o1) + (o2 + o3);

            float cw = (st == 0 || st == 3) ? (DT / 6.f) : (DT / 3.f);
            zsum = fmaf(cw, o, zsum);
            float vn;
            if (st < 3) {
                float cin = (st == 2) ? DT : 0.5f * DT;
                vn = fmaf(cin, o, zc);
            } else {
                zc = zc + zsum;
                vn = zc;
                if (L < 8) ztg[n * 400 + t * 8 + L] = zc;
            }
            #pragma unroll
            for (int i = 0; i < 8; ++i) vu[i] = rl(vn, i);
        }
    }
}

// =====================================================================
// Decoder v3: wave-per-parity-class, lane-per-pixel (LDS col step 1 ->
// <=3-way banks), static class/chunk load balancing, uniform weight loads.
// =====================================================================
template<int CY, int CX>
__device__ __forceinline__ void convt2_run(
    int ch, int L,
    const float (*y1p)[16][10][10],
    float (*y2p)[8][16][16],
    const float* __restrict__ Wc2, const float* __restrict__ db2)
{
    constexpr int NY = CY ? 2 : 3, NX = CX ? 2 : 3, NT = NY * NX;
    constexpr int OFF = (CY == 0) ? (CX == 0 ? 0 : 1152) : (CX == 0 ? 1920 : 2688);
    int g = ch * 64 + L;
    if (g >= 196) return;
    int s = g / 49, p = g % 49, i = p / 7, j = p % 7;
    float acc[8];
    #pragma unroll
    for (int oc = 0; oc < 8; ++oc) acc[oc] = db2[oc];
    const float* wc = Wc2 + OFF;
    #pragma unroll 2
    for (int ic = 0; ic < 16; ++ic) {
        float yv[NT];
        #pragma unroll
        for (int dy = 0; dy < NY; ++dy)
            #pragma unroll
            for (int dx = 0; dx < NX; ++dx)
                yv[dy * NX + dx] = y1p[s][ic][i + dy + CY][j + dx + CX];
        const float* w = wc + ic * 8 * NT;
        #pragma unroll
        for (int oc = 0; oc < 8; ++oc)
            #pragma unroll
            for (int t = 0; t < NT; ++t)
                acc[oc] = fmaf(w[oc * NT + t], yv[t], acc[oc]);
    }
    #pragma unroll
    for (int oc = 0; oc < 8; ++oc)
        y2p[s][oc][1 + 2 * i + CY][1 + 2 * j + CX] = fmaxf(acc[oc], 0.f);
}

template<int CY, int CX>
__device__ __forceinline__ void convt3_run(
    int ch, int L, int blk,
    const float (*y2p)[8][16][16],
    const float* __restrict__ Wc3, float b3v,
    const float* __restrict__ X, float* __restrict__ xrec, float& part)
{
    constexpr int NY = CY ? 2 : 3, NX = CX ? 2 : 3, NT = NY * NX;
    constexpr int OFF = (CY == 0) ? (CX == 0 ? 0 : 72) : (CX == 0 ? 120 : 168);
    int g = ch * 64 + L;
    if (g >= 784) return;
    int s = g / 196, p = g % 196, U = p / 14, V = p % 14;
    const float* wc = Wc3 + OFF;
    float acc = b3v;
    #pragma unroll
    for (int ic = 0; ic < 8; ++ic)
        #pragma unroll
        for (int dy = 0; dy < NY; ++dy)
            #pragma unroll
            for (int dx = 0; dx < NX; ++dx)
                acc = fmaf(wc[ic * NT + dy * NX + dx],
                           y2p[s][ic][U + dy + CY][V + dx + CX], acc);
    float pr = 1.f / (1.f + __expf(-acc));
    size_t o = (size_t)blk * 3136 + s * 784 + (2 * U + CY) * 28 + (2 * V + CX);
    xrec[o] = pr;
    float x = X[o];
    part += __logf(EPSL + pr) * x + __logf(EPSL + 1.f - pr) * (1.f - x);
}

__global__ __launch_bounds__(256) void dec_kernel(
    const float* __restrict__ M1p, const float* __restrict__ zt,
    const float* __restrict__ Wc2, const float* __restrict__ db2,
    const float* __restrict__ Wc3, const float* __restrict__ db3,
    const float* __restrict__ X, float* __restrict__ xrec,
    float* __restrict__ lhp)
{
    __shared__ float y1p[4][16][10][10];   // halo-padded 7x7 -> 10x10 (rows stride 10)
    __shared__ float y2p[4][8][16][16];    // halo-padded 14x14 -> 16x16
    __shared__ float red[256];
    int blk = blockIdx.x, tid = threadIdx.x;
    int w = tid >> 6, L = tid & 63;

    for (int idx = tid; idx < 6400; idx += 256) ((float*)y1p)[idx] = 0.f;
    for (int idx = tid; idx < 8192; idx += 256) ((float*)y2p)[idx] = 0.f;
    __syncthreads();

    // phase 0: y1 = relu(M1 @ z + b) for 4 samples
    {
        float zr[4][8];
        const float* zp = zt + (size_t)blk * 32;
        #pragma unroll
        for (int s = 0; s < 4; ++s)
            #pragma unroll
            for (int jj = 0; jj < 8; ++jj) zr[s][jj] = zp[s * 8 + jj];
        for (int m = tid; m < 784; m += 256) {
            const float4* row = (const float4*)(M1p + m * 12);
            float4 r0 = row[0], r1 = row[1], r2 = row[2];
            int oc = m / 49, r = m % 49, oy = r / 7, ox = r % 7;
            #pragma unroll
            for (int s = 0; s < 4; ++s) {
                float acc = r2.x;
                acc += r0.x * zr[s][0] + r0.y * zr[s][1] + r0.z * zr[s][2] + r0.w * zr[s][3]
                     + r1.x * zr[s][4] + r1.y * zr[s][5] + r1.z * zr[s][6] + r1.w * zr[s][7];
                y1p[s][oc][1 + oy][1 + ox] = fmaxf(acc, 0.f);
            }
        }
    }
    __syncthreads();

    // phase 1: convT2 (16->8, 7->14). 16 (cls,chunk) items balanced across
    // 4 waves by tap count: w0/w1: cls0(9)+cls3(4), w2: cls1(6), w3: cls2(6).
    {
        unsigned word = (w == 0) ? 0xDC10u : (w == 1) ? 0xFE32u
                      : (w == 2) ? 0x7654u : 0xBA98u;
        #pragma unroll
        for (int it = 0; it < 4; ++it) {
            unsigned nib = (word >> (4 * it)) & 15u;
            int cls = nib >> 2, ch = (int)(nib & 3u);
            switch (cls) {
                case 0: convt2_run<0, 0>(ch, L, y1p, y2p, Wc2, db2); break;
                case 1: convt2_run<0, 1>(ch, L, y1p, y2p, Wc2, db2); break;
                case 2: convt2_run<1, 0>(ch, L, y1p, y2p, Wc2, db2); break;
                default: convt2_run<1, 1>(ch, L, y1p, y2p, Wc2, db2); break;
            }
        }
    }
    __syncthreads();

    // phase 2: convT3 (8->1, 14->28) + sigmoid + lhood. 52 (cls,chunk)
    // items, 13 chunks/class, balanced: w0:c0x9 | w1:c0x4+c1x7 |
    // w2:c1x6+c2x8 | w3:c2x5+c3x13.
    float part = 0.f;
    {
        float b3v = db3[0];
        int aCls   = (w < 2) ? 0 : (w == 2 ? 1 : 2);
        int aStart = (w == 0) ? 0 : (w == 1) ? 9 : (w == 2) ? 7 : 8;
        int aCnt   = (w == 0) ? 9 : (w == 1) ? 4 : (w == 2) ? 6 : 5;
        int bCls   = (w == 1) ? 1 : (w == 2) ? 2 : 3;
        int bCnt   = (w == 0) ? 0 : (w == 1) ? 7 : (w == 2) ? 8 : 13;
        for (int c = 0; c < aCnt; ++c) {
            int ch = aStart + c;
            switch (aCls) {
                case 0: convt3_run<0, 0>(ch, L, blk, y2p, Wc3, b3v, X, xrec, part); break;
                case 1: convt3_run<0, 1>(ch, L, blk, y2p, Wc3, b3v, X, xrec, part); break;
                default: convt3_run<1, 0>(ch, L, blk, y2p, Wc3, b3v, X, xrec, part); break;
            }
        }
        for (int c = 0; c < bCnt; ++c) {
            switch (bCls) {
                case 1: convt3_run<0, 1>(c, L, blk, y2p, Wc3, b3v, X, xrec, part); break;
                case 2: convt3_run<1, 0>(c, L, blk, y2p, Wc3, b3v, X, xrec, part); break;
                default: convt3_run<1, 1>(c, L, blk, y2p, Wc3, b3v, X, xrec, part); break;
            }
        }
    }
    red[tid] = part;
    __syncthreads();
    for (int st = 128; st > 0; st >>= 1) {
        if (tid < st) red[tid] += red[tid + st];
        __syncthreads();
    }
    if (tid == 0) lhp[blk] = red[0];
}

// =====================================================================
// Finalize
// =====================================================================
__global__ __launch_bounds__(256) void fin_kernel(
    const float* __restrict__ lhp, const float* __restrict__ klp,
    float* __restrict__ out)
{
    __shared__ double red[256];
    int tid = threadIdx.x;
    double s = 0.0;
    for (int i = tid; i < 3200; i += 256) s += (double)lhp[i];
    red[tid] = s;
    __syncthreads();
    for (int st = 128; st > 0; st >>= 1) {
        if (tid < st) red[tid] += red[tid + st];
        __syncthreads();
    }
    double lh = red[0];
    __syncthreads();
    red[tid] = (double)klp[tid];
    __syncthreads();
    for (int st = 128; st > 0; st >>= 1) {
        if (tid < st) red[tid] += red[tid + st];
        __syncthreads();
    }
    if (tid == 0) {
        out[LH_OFF] = (float)(lh / 256.0);
        out[KL_OFF] = (float)(red[0] / 2048.0);
    }
}

extern "C" void kernel_launch(void* const* d_in, const int* in_sizes, int n_in,
                              void* d_out, int out_size, void* d_ws, size_t ws_size,
                              hipStream_t stream) {
    const float* X     = (const float*)d_in[0];
    const float* eps   = (const float*)d_in[1];
    const float* ew1   = (const float*)d_in[2];
    const float* eb1   = (const float*)d_in[3];
    const float* ew2   = (const float*)d_in[4];
    const float* eb2   = (const float*)d_in[5];
    const float* ew3   = (const float*)d_in[6];
    const float* eb3   = (const float*)d_in[7];
    const float* fc1w  = (const float*)d_in[8];
    const float* fc1b  = (const float*)d_in[9];
    const float* fc2w  = (const float*)d_in[10];
    const float* fc2b  = (const float*)d_in[11];
    const float* fw1   = (const float*)d_in[12];
    const float* fb1   = (const float*)d_in[13];
    const float* fw2   = (const float*)d_in[14];
    const float* fb2   = (const float*)d_in[15];
    const float* fw3   = (const float*)d_in[16];
    const float* fb3   = (const float*)d_in[17];
    const float* fc3w  = (const float*)d_in[18];
    const float* fc3b  = (const float*)d_in[19];
    const float* dw1   = (const float*)d_in[20];
    const float* db1   = (const float*)d_in[21];
    const float* dw2   = (const float*)d_in[22];
    const float* db2   = (const float*)d_in[23];
    const float* dw3   = (const float*)d_in[24];
    const float* db3   = (const float*)d_in[25];

    float* out = (float*)d_out;
    char* ws = (char*)d_ws;
    float* lhp = (float*)ws;
    float* klp = (float*)(ws + 12800);
    float* z0  = (float*)(ws + 13824);
    float* M1p = (float*)(ws + 22016);
    float* Wc2 = (float*)(ws + 59648);
    float* Wc3 = (float*)(ws + 72448);

    prep_kernel<<<51, 256, 0, stream>>>(fc3w, fc3b, dw1, db1, dw2, dw3, M1p, Wc2, Wc3);
    enc_kernel<<<256, 256, 0, stream>>>(X, eps, ew1, eb1, ew2, eb2, ew3, eb3,
                                        fc1w, fc1b, fc2w, fc2b, out, z0, klp);
    ode_kernel<<<256, 64, 0, stream>>>(z0, fw1, fb1, fw2, fb2, fw3, fb3, out + ZT_OFF);
    dec_kernel<<<3200, 256, 0, stream>>>(M1p, out + ZT_OFF, Wc2, db2, Wc3, db3,
                                         X, out + XREC_OFF, lhp);
    fin_kernel<<<1, 256, 0, stream>>>(lhp, klp, out);
}

// Round 5
// 603.416 us; speedup vs baseline: 1.1923x; 1.1923x over previous
//
#include <hip/hip_runtime.h>
#include <math.h>

#define DT 0.1f
#define EPSL 1e-5f

// ---- output layout (float32, concatenated in reference return order) ----
#define XREC_OFF 0
#define QM_OFF   10035200
#define QV_OFF   10037248
#define ZT_OFF   10039296
#define LH_OFF   10141696
#define KL_OFF   10141697

// ---- workspace layout (bytes) ----
// lhp  float[3200]   @ 0
// klp  float[256]    @ 12800
// z0   float[2048]   @ 13824
// M1p  float[784*12] @ 22016
// Wc2  float[3200]   @ 59648
// Wc3  float[200]    @ 72448

// =====================================================================
// Prep: build M1p + parity-class repacked decoder weights.
// =====================================================================
__global__ __launch_bounds__(256) void prep_kernel(
    const float* __restrict__ fc3w, const float* __restrict__ fc3b,
    const float* __restrict__ dw1, const float* __restrict__ db1,
    const float* __restrict__ dw2, const float* __restrict__ dw3,
    float* __restrict__ M1p, float* __restrict__ Wc2, float* __restrict__ Wc3)
{
    int idx = blockIdx.x * 256 + threadIdx.x;
    if (idx < 9408) {                       // M1p [784][12]
        int m = idx / 12, j = idx % 12;
        float acc = 0.f;
        if (j < 9) {
            int oc = m / 49, r = m % 49, oy = r / 7, ox = r % 7;
            acc = (j == 8) ? db1[oc] : 0.f;
            for (int ky = 0; ky < 5; ++ky) {
                int ty = oy + ky - 2;
                if (ty < 0 || (ty & 1)) continue;
                int iy = ty >> 1; if (iy >= 4) continue;
                for (int kx = 0; kx < 5; ++kx) {
                    int tx = ox + kx - 2;
                    if (tx < 0 || (tx & 1)) continue;
                    int ix = tx >> 1; if (ix >= 4) continue;
                    for (int ic = 0; ic < 32; ++ic) {
                        float wv = dw1[((oc * 32 + ic) * 5 + ky) * 5 + kx];
                        int mi = ic * 16 + iy * 4 + ix;
                        acc += wv * ((j < 8) ? fc3w[mi * 8 + j] : fc3b[mi]);
                    }
                }
            }
        }
        M1p[idx] = acc;
    } else if (idx < 9408 + 3200) {         // Wc2 repack, dw2 [oc=8][ic=16][ky][kx]
        int iw = idx - 9408;
        int kx = iw % 5, t1 = iw / 5, ky = t1 % 5, t2 = t1 / 5, ic = t2 % 16, oc = t2 / 16;
        int cy = ky & 1, cx = kx & 1, dy = ky >> 1, dx = kx >> 1;
        int ny = cy ? 2 : 3, nx = cx ? 2 : 3, nt = ny * nx;
        const int off2[4] = {0, 1152, 1920, 2688};
        Wc2[off2[cy * 2 + cx] + (ic * 8 + oc) * nt + dy * nx + dx] = dw2[iw];
    } else if (idx < 9408 + 3200 + 200) {   // Wc3 repack
        int iw = idx - 12608;
        int kx = iw % 5, t1 = iw / 5, ky = t1 % 5, ic = t1 / 5;
        int cy = ky & 1, cx = kx & 1, dy = ky >> 1, dx = kx >> 1;
        int ny = cy ? 2 : 3, nx = cx ? 2 : 3, nt = ny * nx;
        const int off3[4] = {0, 72, 120, 168};
        Wc3[off3[cy * 2 + cx] + ic * nt + dy * nx + dx] = dw3[iw];
    }
}

// =====================================================================
// Encoder v2: branchless padded convs, weights staged in LDS, parallel fc.
// =====================================================================
__global__ __launch_bounds__(256) void enc_kernel(
    const float* __restrict__ X, const float* __restrict__ eps,
    const float* __restrict__ w1, const float* __restrict__ b1,
    const float* __restrict__ w2, const float* __restrict__ b2,
    const float* __restrict__ w3, const float* __restrict__ b3,
    const float* __restrict__ fc1w, const float* __restrict__ fc1b,
    const float* __restrict__ fc2w, const float* __restrict__ fc2b,
    float* __restrict__ out, float* __restrict__ z0, float* __restrict__ klp)
{
    __shared__ float imgp[33][33];     // img at [2+y][2+x]
    __shared__ float a1p[8][17][17];   // a1 at [ic][2+y][2+x]
    __shared__ float a2p[16][11][11];  // a2 at [ic][2+y][2+x]
    __shared__ float h[512];
    __shared__ float w1s[200];
    __shared__ float w2s[3200];
    __shared__ float w3s[12800];
    __shared__ float fcred[16];
    __shared__ float kl_s[8];
    int n = blockIdx.x, tid = threadIdx.x;

    for (int i = tid; i < 1089; i += 256) ((float*)imgp)[i] = 0.f;
    for (int i = tid; i < 2312; i += 256) ((float*)a1p)[i] = 0.f;
    for (int i = tid; i < 1936; i += 256) ((float*)a2p)[i] = 0.f;
    for (int i = tid; i < 50;   i += 256) ((float4*)w1s)[i] = ((const float4*)w1)[i];
    for (int i = tid; i < 800;  i += 256) ((float4*)w2s)[i] = ((const float4*)w2)[i];
    for (int i = tid; i < 3200; i += 256) ((float4*)w3s)[i] = ((const float4*)w3)[i];
    __syncthreads();

    const float* xi = X + (size_t)n * 39200;
    for (int i = tid; i < 784; i += 256) imgp[2 + i / 28][2 + i % 28] = xi[i];
    __syncthreads();

    // conv1: 1->8, 28->14
    for (int idx = tid; idx < 1568; idx += 256) {
        int oc = idx / 196, r = idx % 196, oy = r / 14, ox = r % 14;
        float acc = b1[oc];
        const float* wp = w1s + oc * 25;
        #pragma unroll
        for (int ky = 0; ky < 5; ++ky)
            #pragma unroll
            for (int kx = 0; kx < 5; ++kx)
                acc = fmaf(wp[ky * 5 + kx], imgp[2 * oy + ky][2 * ox + kx], acc);
        a1p[oc][2 + oy][2 + ox] = fmaxf(acc, 0.f);
    }
    __syncthreads();

    // conv2: 8->16, 14->7
    for (int idx = tid; idx < 784; idx += 256) {
        int oc = idx / 49, r = idx % 49, oy = r / 7, ox = r % 7;
        float acc = b2[oc];
        #pragma unroll 2
        for (int ic = 0; ic < 8; ++ic) {
            const float* wp = w2s + (oc * 8 + ic) * 25;
            #pragma unroll
            for (int ky = 0; ky < 5; ++ky)
                #pragma unroll
                for (int kx = 0; kx < 5; ++kx)
                    acc = fmaf(wp[ky * 5 + kx], a1p[ic][2 * oy + ky][2 * ox + kx], acc);
        }
        a2p[oc][2 + oy][2 + ox] = fmaxf(acc, 0.f);
    }
    __syncthreads();

    // conv3: 16->32, 7->4
    for (int idx = tid; idx < 512; idx += 256) {
        int oc = idx / 16, r = idx % 16, oy = r / 4, ox = r % 4;
        float acc = b3[oc];
        #pragma unroll 2
        for (int ic = 0; ic < 16; ++ic) {
            const float* wp = w3s + (oc * 16 + ic) * 25;
            #pragma unroll
            for (int ky = 0; ky < 5; ++ky)
                #pragma unroll
                for (int kx = 0; kx < 5; ++kx)
                    acc = fmaf(wp[ky * 5 + kx], a2p[ic][2 * oy + ky][2 * ox + kx], acc);
        }
        h[oc * 16 + r] = fmaxf(acc, 0.f);
    }
    __syncthreads();

    // fc1/fc2: wave0 -> fc1, wave1 -> fc2; 8-lane stripes + shuffle tree
    if (tid < 128) {
        int wv = tid >> 6, L = tid & 63, o = L >> 3, rr = L & 7;
        const float* fw = (wv ? fc2w : fc1w) + o * 512;
        float p = 0.f;
        #pragma unroll 8
        for (int j = 0; j < 64; ++j) {
            int k = rr + 8 * j;
            p = fmaf(fw[k], h[k], p);
        }
        p += __shfl_down(p, 4, 8);
        p += __shfl_down(p, 2, 8);
        p += __shfl_down(p, 1, 8);
        if (rr == 0) fcred[wv * 8 + o] = p;
    }
    __syncthreads();
    if (tid < 8) {
        float m = fc1b[tid] + fcred[tid];
        float lv = fc2b[tid] + fcred[8 + tid];
        float v = fmaxf(lv, 0.f) + log1pf(expf(-fabsf(lv)));
        float z = m + eps[n * 8 + tid] * v;
        out[QM_OFF + n * 8 + tid] = m;
        out[QV_OFF + n * 8 + tid] = v;
        z0[n * 8 + tid] = z;
        kl_s[tid] = -logf(v) + 0.5f * (v * v + m * m) - 0.5f;
    }
    __syncthreads();
    if (tid == 0) {
        float s = 0.f;
        for (int i = 0; i < 8; ++i) s += kl_s[i];
        klp[n] = s;
    }
}

// =====================================================================
// ODE v3 (unchanged): one wave per sample, register-resident weights.
// =====================================================================
__device__ __forceinline__ float rl(float v, int lane) {
    return __uint_as_float(__builtin_amdgcn_readlane(__float_as_uint(v), lane));
}
__device__ __forceinline__ float bcast(float lo, float hi, int k) {
    return (k < 64) ? rl(lo, k) : rl(hi, k - 64);
}

__global__ __launch_bounds__(64, 1) void ode_kernel(
    const float* __restrict__ z0,
    const float* __restrict__ fw1, const float* __restrict__ fb1,
    const float* __restrict__ fw2, const float* __restrict__ fb2,
    const float* __restrict__ fw3, const float* __restrict__ fb3,
    float* __restrict__ ztg)
{
    int n = blockIdx.x, L = threadIdx.x;
    bool hiv = (L < 36);
    int jA = L, jB = L + 64, i3 = L & 7;

    float w1x[8], w1y[8];
    float w2x[100], w2y[100], w3r[100];
    float b1A = fb1[jA], b1B = hiv ? fb1[jB] : 0.f;
    float b2A = fb2[jA], b2B = hiv ? fb2[jB] : 0.f;
    float b3r = fb3[i3];
    #pragma unroll
    for (int k = 0; k < 8; ++k) {
        w1x[k] = fw1[jA * 8 + k];
        w1y[k] = hiv ? fw1[jB * 8 + k] : 0.f;
    }
    #pragma unroll
    for (int k = 0; k < 100; ++k) {
        w2x[k] = fw2[jA * 100 + k];
        w2y[k] = hiv ? fw2[jB * 100 + k] : 0.f;
        w3r[k] = fw3[i3 * 100 + k];
    }

    float zc = z0[n * 8 + i3];
    if (L < 8) ztg[n * 400 + L] = zc;
    float vu[8];
    #pragma unroll
    for (int i = 0; i < 8; ++i) vu[i] = rl(zc, i);

    #pragma unroll 1
    for (int t = 1; t < 50; ++t) {
        float zsum = 0.f;
        #pragma unroll 1
        for (int st = 0; st < 4; ++st) {
            float aA = b1A, aB = b1B;
            #pragma unroll
            for (int k = 0; k < 8; ++k) {
                aA = fmaf(w1x[k], vu[k], aA);
                aB = fmaf(w1y[k], vu[k], aB);
            }
            aA = fmaxf(aA, 0.f); aB = fmaxf(aB, 0.f);

            float hA0 = b2A, hA1 = 0.f, hA2 = 0.f, hA3 = 0.f;
            float hB0 = b2B, hB1 = 0.f, hB2 = 0.f, hB3 = 0.f;
            #pragma unroll
            for (int k = 0; k < 100; k += 4) {
                float s0 = bcast(aA, aB, k + 0);
                float s1 = bcast(aA, aB, k + 1);
                float s2 = bcast(aA, aB, k + 2);
                float s3 = bcast(aA, aB, k + 3);
                hA0 = fmaf(w2x[k + 0], s0, hA0); hB0 = fmaf(w2y[k + 0], s0, hB0);
                hA1 = fmaf(w2x[k + 1], s1, hA1); hB1 = fmaf(w2y[k + 1], s1, hB1);
                hA2 = fmaf(w2x[k + 2], s2, hA2); hB2 = fmaf(w2y[k + 2], s2, hB2);
                hA3 = fmaf(w2x[k + 3], s3, hA3); hB3 = fmaf(w2y[k + 3], s3, hB3);
            }
            float hA = fmaxf((hA0 + hA1) + (hA2 + hA3), 0.f);
            float hB = fmaxf((hB0 + hB1) + (hB2 + hB3), 0.f);

            float o0 = b3r, o1 = 0.f, o2 = 0.f, o3 = 0.f;
            #pragma unroll
            for (int k = 0; k < 100; k += 4) {
                o0 = fmaf(w3r[k + 0], bcast(hA, hB, k + 0), o0);
                o1 = fmaf(w3r[k + 1], bcast(hA, hB, k + 1), o1);
                o2 = fmaf(w3r[k + 2], bcast(hA, hB, k + 2), o2);
                o3 = fmaf(w3r[k + 3], bcast(hA, hB, k + 3), o3);
            }
            float o = (o0 + o1) + (o2 + o3);

            float cw = (st == 0 || st == 3) ? (DT / 6.f) : (DT / 3.f);
            zsum = fmaf(cw, o, zsum);
            float vn;
            if (st < 3) {
                float cin = (st == 2) ? DT : 0.5f * DT;
                vn = fmaf(cin, o, zc);
            } else {
                zc = zc + zsum;
                vn = zc;
                if (L < 8) ztg[n * 400 + t * 8 + L] = zc;
            }
            #pragma unroll
            for (int i = 0; i < 8; ++i) vu[i] = rl(vn, i);
        }
    }
}

// =====================================================================
// Decoder v5: fused 4-class 2x2 union tiles. Phase1: lane=(s,m,n) m,n<7,
// 32 reg accs, 9 union reads/ic. Phase2: lane=(s,m,n) m,n<14, 4 accs,
// 9 union reads/ic. y2p rows padded to 17 (odd) -> ~conflict-free.
// =====================================================================
__global__ __launch_bounds__(256) void dec_kernel(
    const float* __restrict__ M1p, const float* __restrict__ zt,
    const float* __restrict__ Wc2, const float* __restrict__ db2,
    const float* __restrict__ Wc3, const float* __restrict__ db3,
    const float* __restrict__ X, float* __restrict__ xrec,
    float* __restrict__ lhp)
{
    __shared__ float y1p[4][16][9][10];    // y1 (7x7) at [1+iy][1+ix]; pads zero
    __shared__ float y2p[4][8][16][17];    // y2 (14x14) at [1+iy][1+ix]; pads zero
    __shared__ float red[256];
    int blk = blockIdx.x, tid = threadIdx.x;
    int wv = tid >> 6, L = tid & 63;

    for (int i = tid; i < 1440; i += 256) ((float4*)y1p)[i] = float4{0.f, 0.f, 0.f, 0.f};
    for (int i = tid; i < 2176; i += 256) ((float4*)y2p)[i] = float4{0.f, 0.f, 0.f, 0.f};
    __syncthreads();

    // phase 0: y1 = relu(M1 @ z + b) for 4 samples
    {
        float zr[4][8];
        const float* zp = zt + (size_t)blk * 32;
        #pragma unroll
        for (int s = 0; s < 4; ++s)
            #pragma unroll
            for (int jj = 0; jj < 8; ++jj) zr[s][jj] = zp[s * 8 + jj];
        for (int m = tid; m < 784; m += 256) {
            const float4* row = (const float4*)(M1p + m * 12);
            float4 r0 = row[0], r1 = row[1], r2 = row[2];
            int oc = m / 49, r = m % 49, oy = r / 7, ox = r % 7;
            #pragma unroll
            for (int s = 0; s < 4; ++s) {
                float acc = r2.x;
                acc += r0.x * zr[s][0] + r0.y * zr[s][1] + r0.z * zr[s][2] + r0.w * zr[s][3]
                     + r1.x * zr[s][4] + r1.y * zr[s][5] + r1.z * zr[s][6] + r1.w * zr[s][7];
                y1p[s][oc][1 + oy][1 + ox] = fmaxf(acc, 0.f);
            }
        }
    }
    __syncthreads();

    // phase 1: convT2 fused 4-class 2x2 tiles. wave -> sample, lane -> (m,n).
    if (L < 49) {
        int s = wv, m = L / 7, n = L % 7;
        float acc[4][8];
        #pragma unroll
        for (int oc = 0; oc < 8; ++oc) {
            float b = db2[oc];
            acc[0][oc] = b; acc[1][oc] = b; acc[2][oc] = b; acc[3][oc] = b;
        }
        const float* w00 = Wc2;
        const float* w01 = Wc2 + 1152;
        const float* w10 = Wc2 + 1920;
        const float* w11 = Wc2 + 2688;
        #pragma unroll 2
        for (int ic = 0; ic < 16; ++ic) {
            float yv[3][3];
            #pragma unroll
            for (int ry = 0; ry < 3; ++ry)
                #pragma unroll
                for (int rx = 0; rx < 3; ++rx)
                    yv[ry][rx] = y1p[s][ic][m + ry][n + rx];
            #pragma unroll
            for (int oc = 0; oc < 8; ++oc) {
                const float* p00 = w00 + (ic * 8 + oc) * 9;
                const float* p01 = w01 + (ic * 8 + oc) * 6;
                const float* p10 = w10 + (ic * 8 + oc) * 6;
                const float* p11 = w11 + (ic * 8 + oc) * 4;
                #pragma unroll
                for (int dy = 0; dy < 3; ++dy)
                    #pragma unroll
                    for (int dx = 0; dx < 3; ++dx)
                        acc[0][oc] = fmaf(p00[dy * 3 + dx], yv[dy][dx], acc[0][oc]);
                #pragma unroll
                for (int dy = 0; dy < 3; ++dy)
                    #pragma unroll
                    for (int dx = 0; dx < 2; ++dx)
                        acc[1][oc] = fmaf(p01[dy * 2 + dx], yv[dy][dx + 1], acc[1][oc]);
                #pragma unroll
                for (int dy = 0; dy < 2; ++dy)
                    #pragma unroll
                    for (int dx = 0; dx < 3; ++dx)
                        acc[2][oc] = fmaf(p10[dy * 3 + dx], yv[dy + 1][dx], acc[2][oc]);
                #pragma unroll
                for (int dy = 0; dy < 2; ++dy)
                    #pragma unroll
                    for (int dx = 0; dx < 2; ++dx)
                        acc[3][oc] = fmaf(p11[dy * 2 + dx], yv[dy + 1][dx + 1], acc[3][oc]);
            }
        }
        #pragma unroll
        for (int oc = 0; oc < 8; ++oc) {
            y2p[s][oc][1 + 2 * m][1 + 2 * n]         = fmaxf(acc[0][oc], 0.f);
            y2p[s][oc][1 + 2 * m][1 + 2 * n + 1]     = fmaxf(acc[1][oc], 0.f);
            y2p[s][oc][1 + 2 * m + 1][1 + 2 * n]     = fmaxf(acc[2][oc], 0.f);
            y2p[s][oc][1 + 2 * m + 1][1 + 2 * n + 1] = fmaxf(acc[3][oc], 0.f);
        }
    }
    __syncthreads();

    // phase 2: convT3 fused 4-class 2x2 tiles + sigmoid + lhood
    float part = 0.f;
    {
        float b3v = db3[0];
        const float* q00 = Wc3;
        const float* q01 = Wc3 + 72;
        const float* q10 = Wc3 + 120;
        const float* q11 = Wc3 + 168;
        #pragma unroll 1
        for (int ch = 0; ch < 4; ++ch) {
            int g = ch * 256 + tid;
            if (g < 784) {
                int s2 = g / 196, r2 = g % 196, m = r2 / 14, n = r2 % 14;
                float o00 = b3v, o01 = b3v, o10 = b3v, o11 = b3v;
                #pragma unroll 2
                for (int ic = 0; ic < 8; ++ic) {
                    float yv[3][3];
                    #pragma unroll
                    for (int ry = 0; ry < 3; ++ry)
                        #pragma unroll
                        for (int rx = 0; rx < 3; ++rx)
                            yv[ry][rx] = y2p[s2][ic][m + ry][n + rx];
                    #pragma unroll
                    for (int dy = 0; dy < 3; ++dy)
                        #pragma unroll
                        for (int dx = 0; dx < 3; ++dx)
                            o00 = fmaf(q00[ic * 9 + dy * 3 + dx], yv[dy][dx], o00);
                    #pragma unroll
                    for (int dy = 0; dy < 3; ++dy)
                        #pragma unroll
                        for (int dx = 0; dx < 2; ++dx)
                            o01 = fmaf(q01[ic * 6 + dy * 2 + dx], yv[dy][dx + 1], o01);
                    #pragma unroll
                    for (int dy = 0; dy < 2; ++dy)
                        #pragma unroll
                        for (int dx = 0; dx < 3; ++dx)
                            o10 = fmaf(q10[ic * 6 + dy * 3 + dx], yv[dy + 1][dx], o10);
                    #pragma unroll
                    for (int dy = 0; dy < 2; ++dy)
                        #pragma unroll
                        for (int dx = 0; dx < 2; ++dx)
                            o11 = fmaf(q11[ic * 4 + dy * 2 + dx], yv[dy + 1][dx + 1], o11);
                }
                float p00s = 1.f / (1.f + __expf(-o00));
                float p01s = 1.f / (1.f + __expf(-o01));
                float p10s = 1.f / (1.f + __expf(-o10));
                float p11s = 1.f / (1.f + __expf(-o11));
                size_t base = (size_t)blk * 3136 + s2 * 784 + 2 * m * 28 + 2 * n;
                *(float2*)(xrec + base)      = float2{p00s, p01s};
                *(float2*)(xrec + base + 28) = float2{p10s, p11s};
                float2 x0 = *(const float2*)(X + base);
                float2 x1 = *(const float2*)(X + base + 28);
                part += __logf(EPSL + p00s) * x0.x + __logf(EPSL + 1.f - p00s) * (1.f - x0.x);
                part += __logf(EPSL + p01s) * x0.y + __logf(EPSL + 1.f - p01s) * (1.f - x0.y);
                part += __logf(EPSL + p10s) * x1.x + __logf(EPSL + 1.f - p10s) * (1.f - x1.x);
                part += __logf(EPSL + p11s) * x1.y + __logf(EPSL + 1.f - p11s) * (1.f - x1.y);
            }
        }
    }
    red[tid] = part;
    __syncthreads();
    for (int st = 128; st > 0; st >>= 1) {
        if (tid < st) red[tid] += red[tid + st];
        __syncthreads();
    }
    if (tid == 0) lhp[blk] = red[0];
}

// =====================================================================
// Finalize
// =====================================================================
__global__ __launch_bounds__(256) void fin_kernel(
    const float* __restrict__ lhp, const float* __restrict__ klp,
    float* __restrict__ out)
{
    __shared__ double red[256];
    int tid = threadIdx.x;
    double s = 0.0;
    for (int i = tid; i < 3200; i += 256) s += (double)lhp[i];
    red[tid] = s;
    __syncthreads();
    for (int st = 128; st > 0; st >>= 1) {
        if (tid < st) red[tid] += red[tid + st];
        __syncthreads();
    }
    double lh = red[0];
    __syncthreads();
    red[tid] = (double)klp[tid];
    __syncthreads();
    for (int st = 128; st > 0; st >>= 1) {
        if (tid < st) red[tid] += red[tid + st];
        __syncthreads();
    }
    if (tid == 0) {
        out[LH_OFF] = (float)(lh / 256.0);
        out[KL_OFF] = (float)(red[0] / 2048.0);
    }
}

extern "C" void kernel_launch(void* const* d_in, const int* in_sizes, int n_in,
                              void* d_out, int out_size, void* d_ws, size_t ws_size,
                              hipStream_t stream) {
    const float* X     = (const float*)d_in[0];
    const float* eps   = (const float*)d_in[1];
    const float* ew1   = (const float*)d_in[2];
    const float* eb1   = (const float*)d_in[3];
    const float* ew2   = (const float*)d_in[4];
    const float* eb2   = (const float*)d_in[5];
    const float* ew3   = (const float*)d_in[6];
    const float* eb3   = (const float*)d_in[7];
    const float* fc1w  = (const float*)d_in[8];
    const float* fc1b  = (const float*)d_in[9];
    const float* fc2w  = (const float*)d_in[10];
    const float* fc2b  = (const float*)d_in[11];
    const float* fw1   = (const float*)d_in[12];
    const float* fb1   = (const float*)d_in[13];
    const float* fw2   = (const float*)d_in[14];
    const float* fb2   = (const float*)d_in[15];
    const float* fw3   = (const float*)d_in[16];
    const float* fb3   = (const float*)d_in[17];
    const float* fc3w  = (const float*)d_in[18];
    const float* fc3b  = (const float*)d_in[19];
    const float* dw1   = (const float*)d_in[20];
    const float* db1   = (const float*)d_in[21];
    const float* dw2   = (const float*)d_in[22];
    const float* db2   = (const float*)d_in[23];
    const float* dw3   = (const float*)d_in[24];
    const float* db3   = (const float*)d_in[25];

    float* out = (float*)d_out;
    char* ws = (char*)d_ws;
    float* lhp = (float*)ws;
    float* klp = (float*)(ws + 12800);
    float* z0  = (float*)(ws + 13824);
    float* M1p = (float*)(ws + 22016);
    float* Wc2 = (float*)(ws + 59648);
    float* Wc3 = (float*)(ws + 72448);

    prep_kernel<<<51, 256, 0, stream>>>(fc3w, fc3b, dw1, db1, dw2, dw3, M1p, Wc2, Wc3);
    enc_kernel<<<256, 256, 0, stream>>>(X, eps, ew1, eb1, ew2, eb2, ew3, eb3,
                                        fc1w, fc1b, fc2w, fc2b, out, z0, klp);
    ode_kernel<<<256, 64, 0, stream>>>(z0, fw1, fb1, fw2, fb2, fw3, fb3, out + ZT_OFF);
    dec_kernel<<<3200, 256, 0, stream>>>(M1p, out + ZT_OFF, Wc2, db2, Wc3, db3,
                                         X, out + XREC_OFF, lhp);
    fin_kernel<<<1, 256, 0, stream>>>(lhp, klp, out);
}

// Round 6
// 505.686 us; speedup vs baseline: 1.4227x; 1.1933x over previous
//
#include <hip/hip_runtime.h>
#include <math.h>

#define DT 0.1f
#define EPSL 1e-5f

// ---- output layout (float32, concatenated in reference return order) ----
#define XREC_OFF 0
#define QM_OFF   10035200
#define QV_OFF   10037248
#define ZT_OFF   10039296
#define LH_OFF   10141696
#define KL_OFF   10141697

// ---- workspace layout (bytes) ----
// lhp  float[3200]   @ 0
// klp  float[256]    @ 12800
// z0   float[2048]   @ 13824
// M1p  float[784*12] @ 22016
// Wc2  float[3200]   @ 59648
// Wc3  float[200]    @ 72448

// =====================================================================
// Prep: build M1p + parity-class repacked decoder weights.
// =====================================================================
__global__ __launch_bounds__(256) void prep_kernel(
    const float* __restrict__ fc3w, const float* __restrict__ fc3b,
    const float* __restrict__ dw1, const float* __restrict__ db1,
    const float* __restrict__ dw2, const float* __restrict__ dw3,
    float* __restrict__ M1p, float* __restrict__ Wc2, float* __restrict__ Wc3)
{
    int idx = blockIdx.x * 256 + threadIdx.x;
    if (idx < 9408) {                       // M1p [784][12]
        int m = idx / 12, j = idx % 12;
        float acc = 0.f;
        if (j < 9) {
            int oc = m / 49, r = m % 49, oy = r / 7, ox = r % 7;
            acc = (j == 8) ? db1[oc] : 0.f;
            for (int ky = 0; ky < 5; ++ky) {
                int ty = oy + ky - 2;
                if (ty < 0 || (ty & 1)) continue;
                int iy = ty >> 1; if (iy >= 4) continue;
                for (int kx = 0; kx < 5; ++kx) {
                    int tx = ox + kx - 2;
                    if (tx < 0 || (tx & 1)) continue;
                    int ix = tx >> 1; if (ix >= 4) continue;
                    for (int ic = 0; ic < 32; ++ic) {
                        float wv = dw1[((oc * 32 + ic) * 5 + ky) * 5 + kx];
                        int mi = ic * 16 + iy * 4 + ix;
                        acc += wv * ((j < 8) ? fc3w[mi * 8 + j] : fc3b[mi]);
                    }
                }
            }
        }
        M1p[idx] = acc;
    } else if (idx < 9408 + 3200) {         // Wc2 repack, dw2 [oc=8][ic=16][ky][kx]
        int iw = idx - 9408;
        int kx = iw % 5, t1 = iw / 5, ky = t1 % 5, t2 = t1 / 5, ic = t2 % 16, oc = t2 / 16;
        int cy = ky & 1, cx = kx & 1, dy = ky >> 1, dx = kx >> 1;
        int ny = cy ? 2 : 3, nx = cx ? 2 : 3, nt = ny * nx;
        const int off2[4] = {0, 1152, 1920, 2688};
        Wc2[off2[cy * 2 + cx] + (ic * 8 + oc) * nt + dy * nx + dx] = dw2[iw];
    } else if (idx < 9408 + 3200 + 200) {   // Wc3 repack
        int iw = idx - 12608;
        int kx = iw % 5, t1 = iw / 5, ky = t1 % 5, ic = t1 / 5;
        int cy = ky & 1, cx = kx & 1, dy = ky >> 1, dx = kx >> 1;
        int ny = cy ? 2 : 3, nx = cx ? 2 : 3, nt = ny * nx;
        const int off3[4] = {0, 72, 120, 168};
        Wc3[off3[cy * 2 + cx] + ic * nt + dy * nx + dx] = dw3[iw];
    }
}

// =====================================================================
// Encoder v2 (unchanged): branchless padded convs, LDS weights, parallel fc.
// =====================================================================
__global__ __launch_bounds__(256) void enc_kernel(
    const float* __restrict__ X, const float* __restrict__ eps,
    const float* __restrict__ w1, const float* __restrict__ b1,
    const float* __restrict__ w2, const float* __restrict__ b2,
    const float* __restrict__ w3, const float* __restrict__ b3,
    const float* __restrict__ fc1w, const float* __restrict__ fc1b,
    const float* __restrict__ fc2w, const float* __restrict__ fc2b,
    float* __restrict__ out, float* __restrict__ z0, float* __restrict__ klp)
{
    __shared__ float imgp[33][33];
    __shared__ float a1p[8][17][17];
    __shared__ float a2p[16][11][11];
    __shared__ float h[512];
    __shared__ float w1s[200];
    __shared__ float w2s[3200];
    __shared__ float w3s[12800];
    __shared__ float fcred[16];
    __shared__ float kl_s[8];
    int n = blockIdx.x, tid = threadIdx.x;

    for (int i = tid; i < 1089; i += 256) ((float*)imgp)[i] = 0.f;
    for (int i = tid; i < 2312; i += 256) ((float*)a1p)[i] = 0.f;
    for (int i = tid; i < 1936; i += 256) ((float*)a2p)[i] = 0.f;
    for (int i = tid; i < 50;   i += 256) ((float4*)w1s)[i] = ((const float4*)w1)[i];
    for (int i = tid; i < 800;  i += 256) ((float4*)w2s)[i] = ((const float4*)w2)[i];
    for (int i = tid; i < 3200; i += 256) ((float4*)w3s)[i] = ((const float4*)w3)[i];
    __syncthreads();

    const float* xi = X + (size_t)n * 39200;
    for (int i = tid; i < 784; i += 256) imgp[2 + i / 28][2 + i % 28] = xi[i];
    __syncthreads();

    for (int idx = tid; idx < 1568; idx += 256) {
        int oc = idx / 196, r = idx % 196, oy = r / 14, ox = r % 14;
        float acc = b1[oc];
        const float* wp = w1s + oc * 25;
        #pragma unroll
        for (int ky = 0; ky < 5; ++ky)
            #pragma unroll
            for (int kx = 0; kx < 5; ++kx)
                acc = fmaf(wp[ky * 5 + kx], imgp[2 * oy + ky][2 * ox + kx], acc);
        a1p[oc][2 + oy][2 + ox] = fmaxf(acc, 0.f);
    }
    __syncthreads();

    for (int idx = tid; idx < 784; idx += 256) {
        int oc = idx / 49, r = idx % 49, oy = r / 7, ox = r % 7;
        float acc = b2[oc];
        #pragma unroll 2
        for (int ic = 0; ic < 8; ++ic) {
            const float* wp = w2s + (oc * 8 + ic) * 25;
            #pragma unroll
            for (int ky = 0; ky < 5; ++ky)
                #pragma unroll
                for (int kx = 0; kx < 5; ++kx)
                    acc = fmaf(wp[ky * 5 + kx], a1p[ic][2 * oy + ky][2 * ox + kx], acc);
        }
        a2p[oc][2 + oy][2 + ox] = fmaxf(acc, 0.f);
    }
    __syncthreads();

    for (int idx = tid; idx < 512; idx += 256) {
        int oc = idx / 16, r = idx % 16, oy = r / 4, ox = r % 4;
        float acc = b3[oc];
        #pragma unroll 2
        for (int ic = 0; ic < 16; ++ic) {
            const float* wp = w3s + (oc * 16 + ic) * 25;
            #pragma unroll
            for (int ky = 0; ky < 5; ++ky)
                #pragma unroll
                for (int kx = 0; kx < 5; ++kx)
                    acc = fmaf(wp[ky * 5 + kx], a2p[ic][2 * oy + ky][2 * ox + kx], acc);
        }
        h[oc * 16 + r] = fmaxf(acc, 0.f);
    }
    __syncthreads();

    if (tid < 128) {
        int wv = tid >> 6, L = tid & 63, o = L >> 3, rr = L & 7;
        const float* fw = (wv ? fc2w : fc1w) + o * 512;
        float p = 0.f;
        #pragma unroll 8
        for (int j = 0; j < 64; ++j) {
            int k = rr + 8 * j;
            p = fmaf(fw[k], h[k], p);
        }
        p += __shfl_down(p, 4, 8);
        p += __shfl_down(p, 2, 8);
        p += __shfl_down(p, 1, 8);
        if (rr == 0) fcred[wv * 8 + o] = p;
    }
    __syncthreads();
    if (tid < 8) {
        float m = fc1b[tid] + fcred[tid];
        float lv = fc2b[tid] + fcred[8 + tid];
        float v = fmaxf(lv, 0.f) + log1pf(expf(-fabsf(lv)));
        float z = m + eps[n * 8 + tid] * v;
        out[QM_OFF + n * 8 + tid] = m;
        out[QV_OFF + n * 8 + tid] = v;
        z0[n * 8 + tid] = z;
        kl_s[tid] = -logf(v) + 0.5f * (v * v + m * m) - 0.5f;
    }
    __syncthreads();
    if (tid == 0) {
        float s = 0.f;
        for (int i = 0; i < 8; ++i) s += kl_s[i];
        klp[n] = s;
    }
}

// =====================================================================
// ODE v4: 4 waves per sample, k-split 25 per wave. Layer1 computed by
// lanes 0..24 of each wave for its own k-range -> all layer-2/3
// broadcasts are intra-wave readlanes. Two LDS reduces + 2 barriers
// per RK4 stage. Weight slices in VGPRs (~120 regs).
// =====================================================================
__device__ __forceinline__ float rl(float v, int lane) {
    return __uint_as_float(__builtin_amdgcn_readlane(__float_as_uint(v), lane));
}

__global__ __launch_bounds__(256, 1) void ode_kernel(
    const float* __restrict__ z0,
    const float* __restrict__ fw1, const float* __restrict__ fb1,
    const float* __restrict__ fw2, const float* __restrict__ fb2,
    const float* __restrict__ fw3, const float* __restrict__ fb3,
    float* __restrict__ ztg)
{
    __shared__ float part2[4][104];
    __shared__ float part3[4][8];
    int n = blockIdx.x, tid = threadIdx.x;
    int w = tid >> 6, L = tid & 63;
    int i3 = L & 7;
    bool act25 = (L < 25);
    int j1 = 25 * w + L;                 // layer1/reduce output (lanes<25)
    bool hiv = (L < 36);
    int jA = L, jB = L + 64;
    int k0 = 25 * w;

    // ---- register-resident weight slices ----
    float w1r[8];
    float b1A = 0.f, b2A = 0.f;
    if (act25) {
        b1A = fb1[j1];
        b2A = fb2[j1];
        #pragma unroll
        for (int k = 0; k < 8; ++k) w1r[k] = fw1[j1 * 8 + k];
    } else {
        #pragma unroll
        for (int k = 0; k < 8; ++k) w1r[k] = 0.f;
    }
    float w2x[25], w2y[25], w3r[25];
    #pragma unroll
    for (int kk = 0; kk < 25; ++kk) {
        w2x[kk] = fw2[jA * 100 + k0 + kk];
        w2y[kk] = hiv ? fw2[jB * 100 + k0 + kk] : 0.f;
        w3r[kk] = fw3[i3 * 100 + k0 + kk];
    }
    float b3r = fb3[i3];

    float zc = z0[n * 8 + i3];           // every lane: dim L&7 (replicated)
    if (tid < 8) ztg[n * 400 + tid] = zc;
    float vu[8];
    #pragma unroll
    for (int i = 0; i < 8; ++i) vu[i] = rl(zc, i);

    #pragma unroll 1
    for (int t = 1; t < 50; ++t) {
        float zsum = 0.f;
        #pragma unroll 1
        for (int st = 0; st < 4; ++st) {
            // ---- layer 1 (lanes 0..24 of each wave): a1[k0+L] ----
            float aA = 0.f;
            if (act25) {
                float a = b1A;
                #pragma unroll
                for (int k = 0; k < 8; ++k) a = fmaf(w1r[k], vu[k], a);
                aA = fmaxf(a, 0.f);
            }

            // ---- layer 2 partial: 25 intra-wave bcasts, 2 outputs/lane ----
            float ha[4] = {0.f, 0.f, 0.f, 0.f};
            float hb[4] = {0.f, 0.f, 0.f, 0.f};
            #pragma unroll
            for (int kk = 0; kk < 25; ++kk) {
                float s = rl(aA, kk);
                ha[kk & 3] = fmaf(w2x[kk], s, ha[kk & 3]);
                hb[kk & 3] = fmaf(w2y[kk], s, hb[kk & 3]);
            }
            part2[w][L] = (ha[0] + ha[1]) + (ha[2] + ha[3]);
            if (hiv) part2[w][64 + L] = (hb[0] + hb[1]) + (hb[2] + hb[3]);
            __syncthreads();

            // ---- layer 2 reduce (lanes 0..24): h2[k0+L] ----
            float h2v = 0.f;
            if (act25) {
                float sA = (part2[0][j1] + part2[1][j1]) + (part2[2][j1] + part2[3][j1]);
                h2v = fmaxf(b2A + sA, 0.f);
            }

            // ---- layer 3 partial: 25 intra-wave bcasts, out dim L&7 ----
            float oa[4] = {0.f, 0.f, 0.f, 0.f};
            #pragma unroll
            for (int kk = 0; kk < 25; ++kk) {
                float s = rl(h2v, kk);
                oa[kk & 3] = fmaf(w3r[kk], s, oa[kk & 3]);
            }
            if (L < 8) part3[w][L] = (oa[0] + oa[1]) + (oa[2] + oa[3]);
            __syncthreads();

            // ---- final sum + RK4 (replicated in every lane) ----
            float o = b3r + ((part3[0][i3] + part3[1][i3]) + (part3[2][i3] + part3[3][i3]));
            float cw = (st == 0 || st == 3) ? (DT / 6.f) : (DT / 3.f);
            zsum = fmaf(cw, o, zsum);
            float vn;
            if (st < 3) {
                float cin = (st == 2) ? DT : 0.5f * DT;
                vn = fmaf(cin, o, zc);
            } else {
                zc = zc + zsum;
                vn = zc;
                if (tid < 8) ztg[n * 400 + t * 8 + tid] = zc;
            }
            #pragma unroll
            for (int i = 0; i < 8; ++i) vu[i] = rl(vn, i);
        }
    }
}

// =====================================================================
// Decoder v5 (unchanged): fused 4-class 2x2 union tiles.
// =====================================================================
__global__ __launch_bounds__(256) void dec_kernel(
    const float* __restrict__ M1p, const float* __restrict__ zt,
    const float* __restrict__ Wc2, const float* __restrict__ db2,
    const float* __restrict__ Wc3, const float* __restrict__ db3,
    const float* __restrict__ X, float* __restrict__ xrec,
    float* __restrict__ lhp)
{
    __shared__ float y1p[4][16][9][10];
    __shared__ float y2p[4][8][16][17];
    __shared__ float red[256];
    int blk = blockIdx.x, tid = threadIdx.x;
    int wv = tid >> 6, L = tid & 63;

    for (int i = tid; i < 1440; i += 256) ((float4*)y1p)[i] = float4{0.f, 0.f, 0.f, 0.f};
    for (int i = tid; i < 2176; i += 256) ((float4*)y2p)[i] = float4{0.f, 0.f, 0.f, 0.f};
    __syncthreads();

    {
        float zr[4][8];
        const float* zp = zt + (size_t)blk * 32;
        #pragma unroll
        for (int s = 0; s < 4; ++s)
            #pragma unroll
            for (int jj = 0; jj < 8; ++jj) zr[s][jj] = zp[s * 8 + jj];
        for (int m = tid; m < 784; m += 256) {
            const float4* row = (const float4*)(M1p + m * 12);
            float4 r0 = row[0], r1 = row[1], r2 = row[2];
            int oc = m / 49, r = m % 49, oy = r / 7, ox = r % 7;
            #pragma unroll
            for (int s = 0; s < 4; ++s) {
                float acc = r2.x;
                acc += r0.x * zr[s][0] + r0.y * zr[s][1] + r0.z * zr[s][2] + r0.w * zr[s][3]
                     + r1.x * zr[s][4] + r1.y * zr[s][5] + r1.z * zr[s][6] + r1.w * zr[s][7];
                y1p[s][oc][1 + oy][1 + ox] = fmaxf(acc, 0.f);
            }
        }
    }
    __syncthreads();

    if (L < 49) {
        int s = wv, m = L / 7, n = L % 7;
        float acc[4][8];
        #pragma unroll
        for (int oc = 0; oc < 8; ++oc) {
            float b = db2[oc];
            acc[0][oc] = b; acc[1][oc] = b; acc[2][oc] = b; acc[3][oc] = b;
        }
        const float* w00 = Wc2;
        const float* w01 = Wc2 + 1152;
        const float* w10 = Wc2 + 1920;
        const float* w11 = Wc2 + 2688;
        #pragma unroll 2
        for (int ic = 0; ic < 16; ++ic) {
            float yv[3][3];
            #pragma unroll
            for (int ry = 0; ry < 3; ++ry)
                #pragma unroll
                for (int rx = 0; rx < 3; ++rx)
                    yv[ry][rx] = y1p[s][ic][m + ry][n + rx];
            #pragma unroll
            for (int oc = 0; oc < 8; ++oc) {
                const float* p00 = w00 + (ic * 8 + oc) * 9;
                const float* p01 = w01 + (ic * 8 + oc) * 6;
                const float* p10 = w10 + (ic * 8 + oc) * 6;
                const float* p11 = w11 + (ic * 8 + oc) * 4;
                #pragma unroll
                for (int dy = 0; dy < 3; ++dy)
                    #pragma unroll
                    for (int dx = 0; dx < 3; ++dx)
                        acc[0][oc] = fmaf(p00[dy * 3 + dx], yv[dy][dx], acc[0][oc]);
                #pragma unroll
                for (int dy = 0; dy < 3; ++dy)
                    #pragma unroll
                    for (int dx = 0; dx < 2; ++dx)
                        acc[1][oc] = fmaf(p01[dy * 2 + dx], yv[dy][dx + 1], acc[1][oc]);
                #pragma unroll
                for (int dy = 0; dy < 2; ++dy)
                    #pragma unroll
                    for (int dx = 0; dx < 3; ++dx)
                        acc[2][oc] = fmaf(p10[dy * 3 + dx], yv[dy + 1][dx], acc[2][oc]);
                #pragma unroll
                for (int dy = 0; dy < 2; ++dy)
                    #pragma unroll
                    for (int dx = 0; dx < 2; ++dx)
                        acc[3][oc] = fmaf(p11[dy * 2 + dx], yv[dy + 1][dx + 1], acc[3][oc]);
            }
        }
        #pragma unroll
        for (int oc = 0; oc < 8; ++oc) {
            y2p[s][oc][1 + 2 * m][1 + 2 * n]         = fmaxf(acc[0][oc], 0.f);
            y2p[s][oc][1 + 2 * m][1 + 2 * n + 1]     = fmaxf(acc[1][oc], 0.f);
            y2p[s][oc][1 + 2 * m + 1][1 + 2 * n]     = fmaxf(acc[2][oc], 0.f);
            y2p[s][oc][1 + 2 * m + 1][1 + 2 * n + 1] = fmaxf(acc[3][oc], 0.f);
        }
    }
    __syncthreads();

    float part = 0.f;
    {
        float b3v = db3[0];
        const float* q00 = Wc3;
        const float* q01 = Wc3 + 72;
        const float* q10 = Wc3 + 120;
        const float* q11 = Wc3 + 168;
        #pragma unroll 1
        for (int ch = 0; ch < 4; ++ch) {
            int g = ch * 256 + tid;
            if (g < 784) {
                int s2 = g / 196, r2 = g % 196, m = r2 / 14, n = r2 % 14;
                float o00 = b3v, o01 = b3v, o10 = b3v, o11 = b3v;
                #pragma unroll 2
                for (int ic = 0; ic < 8; ++ic) {
                    float yv[3][3];
                    #pragma unroll
                    for (int ry = 0; ry < 3; ++ry)
                        #pragma unroll
                        for (int rx = 0; rx < 3; ++rx)
                            yv[ry][rx] = y2p[s2][ic][m + ry][n + rx];
                    #pragma unroll
                    for (int dy = 0; dy < 3; ++dy)
                        #pragma unroll
                        for (int dx = 0; dx < 3; ++dx)
                            o00 = fmaf(q00[ic * 9 + dy * 3 + dx], yv[dy][dx], o00);
                    #pragma unroll
                    for (int dy = 0; dy < 3; ++dy)
                        #pragma unroll
                        for (int dx = 0; dx < 2; ++dx)
                            o01 = fmaf(q01[ic * 6 + dy * 2 + dx], yv[dy][dx + 1], o01);
                    #pragma unroll
                    for (int dy = 0; dy < 2; ++dy)
                        #pragma unroll
                        for (int dx = 0; dx < 3; ++dx)
                            o10 = fmaf(q10[ic * 6 + dy * 3 + dx], yv[dy + 1][dx], o10);
                    #pragma unroll
                    for (int dy = 0; dy < 2; ++dy)
                        #pragma unroll
                        for (int dx = 0; dx < 2; ++dx)
                            o11 = fmaf(q11[ic * 4 + dy * 2 + dx], yv[dy + 1][dx + 1], o11);
                }
                float p00s = 1.f / (1.f + __expf(-o00));
                float p01s = 1.f / (1.f + __expf(-o01));
                float p10s = 1.f / (1.f + __expf(-o10));
                float p11s = 1.f / (1.f + __expf(-o11));
                size_t base = (size_t)blk * 3136 + s2 * 784 + 2 * m * 28 + 2 * n;
                *(float2*)(xrec + base)      = float2{p00s, p01s};
                *(float2*)(xrec + base + 28) = float2{p10s, p11s};
                float2 x0 = *(const float2*)(X + base);
                float2 x1 = *(const float2*)(X + base + 28);
                part += __logf(EPSL + p00s) * x0.x + __logf(EPSL + 1.f - p00s) * (1.f - x0.x);
                part += __logf(EPSL + p01s) * x0.y + __logf(EPSL + 1.f - p01s) * (1.f - x0.y);
                part += __logf(EPSL + p10s) * x1.x + __logf(EPSL + 1.f - p10s) * (1.f - x1.x);
                part += __logf(EPSL + p11s) * x1.y + __logf(EPSL + 1.f - p11s) * (1.f - x1.y);
            }
        }
    }
    red[tid] = part;
    __syncthreads();
    for (int st = 128; st > 0; st >>= 1) {
        if (tid < st) red[tid] += red[tid + st];
        __syncthreads();
    }
    if (tid == 0) lhp[blk] = red[0];
}

// =====================================================================
// Finalize
// =====================================================================
__global__ __launch_bounds__(256) void fin_kernel(
    const float* __restrict__ lhp, const float* __restrict__ klp,
    float* __restrict__ out)
{
    __shared__ double red[256];
    int tid = threadIdx.x;
    double s = 0.0;
    for (int i = tid; i < 3200; i += 256) s += (double)lhp[i];
    red[tid] = s;
    __syncthreads();
    for (int st = 128; st > 0; st >>= 1) {
        if (tid < st) red[tid] += red[tid + st];
        __syncthreads();
    }
    double lh = red[0];
    __syncthreads();
    red[tid] = (double)klp[tid];
    __syncthreads();
    for (int st = 128; st > 0; st >>= 1) {
        if (tid < st) red[tid] += red[tid + st];
        __syncthreads();
    }
    if (tid == 0) {
        out[LH_OFF] = (float)(lh / 256.0);
        out[KL_OFF] = (float)(red[0] / 2048.0);
    }
}

extern "C" void kernel_launch(void* const* d_in, const int* in_sizes, int n_in,
                              void* d_out, int out_size, void* d_ws, size_t ws_size,
                              hipStream_t stream) {
    const float* X     = (const float*)d_in[0];
    const float* eps   = (const float*)d_in[1];
    const float* ew1   = (const float*)d_in[2];
    const float* eb1   = (const float*)d_in[3];
    const float* ew2   = (const float*)d_in[4];
    const float* eb2   = (const float*)d_in[5];
    const float* ew3   = (const float*)d_in[6];
    const float* eb3   = (const float*)d_in[7];
    const float* fc1w  = (const float*)d_in[8];
    const float* fc1b  = (const float*)d_in[9];
    const float* fc2w  = (const float*)d_in[10];
    const float* fc2b  = (const float*)d_in[11];
    const float* fw1   = (const float*)d_in[12];
    const float* fb1   = (const float*)d_in[13];
    const float* fw2   = (const float*)d_in[14];
    const float* fb2   = (const float*)d_in[15];
    const float* fw3   = (const float*)d_in[16];
    const float* fb3   = (const float*)d_in[17];
    const float* fc3w  = (const float*)d_in[18];
    const float* fc3b  = (const float*)d_in[19];
    const float* dw1   = (const float*)d_in[20];
    const float* db1   = (const float*)d_in[21];
    const float* dw2   = (const float*)d_in[22];
    const float* db2   = (const float*)d_in[23];
    const float* dw3   = (const float*)d_in[24];
    const float* db3   = (const float*)d_in[25];

    float* out = (float*)d_out;
    char* ws = (char*)d_ws;
    float* lhp = (float*)ws;
    float* klp = (float*)(ws + 12800);
    float* z0  = (float*)(ws + 13824);
    float* M1p = (float*)(ws + 22016);
    float* Wc2 = (float*)(ws + 59648);
    float* Wc3 = (float*)(ws + 72448);

    prep_kernel<<<51, 256, 0, stream>>>(fc3w, fc3b, dw1, db1, dw2, dw3, M1p, Wc2, Wc3);
    enc_kernel<<<256, 256, 0, stream>>>(X, eps, ew1, eb1, ew2, eb2, ew3, eb3,
                                        fc1w, fc1b, fc2w, fc2b, out, z0, klp);
    ode_kernel<<<256, 256, 0, stream>>>(z0, fw1, fb1, fw2, fb2, fw3, fb3, out + ZT_OFF);
    dec_kernel<<<3200, 256, 0, stream>>>(M1p, out + ZT_OFF, Wc2, db2, Wc3, db3,
                                         X, out + XREC_OFF, lhp);
    fin_kernel<<<1, 256, 0, stream>>>(lhp, klp, out);
}

// Round 7
// 484.564 us; speedup vs baseline: 1.4847x; 1.0436x over previous
//
#include <hip/hip_runtime.h>
#include <math.h>

#define DT 0.1f
#define EPSL 1e-5f

// ---- output layout (float32, concatenated in reference return order) ----
#define XREC_OFF 0
#define QM_OFF   10035200
#define QV_OFF   10037248
#define ZT_OFF   10039296
#define LH_OFF   10141696
#define KL_OFF   10141697

// ---- workspace layout (bytes) ----
// lhp  float[3200]   @ 0
// klp  float[256]    @ 12800
// z0   float[2048]   @ 13824
// M1p  float[784*12] @ 22016
// Wc2  float[3200]   @ 59648
// Wc3  float[200]    @ 72448

__device__ __forceinline__ unsigned short f2bf(float x) {
    unsigned int u = __float_as_uint(x);
    u += 0x7fffu + ((u >> 16) & 1u);
    return (unsigned short)(u >> 16);
}
__device__ __forceinline__ float bf2f(unsigned short h) {
    return __uint_as_float(((unsigned int)h) << 16);
}

// =====================================================================
// Prep: build M1p + parity-class repacked decoder weights.
// =====================================================================
__global__ __launch_bounds__(256) void prep_kernel(
    const float* __restrict__ fc3w, const float* __restrict__ fc3b,
    const float* __restrict__ dw1, const float* __restrict__ db1,
    const float* __restrict__ dw2, const float* __restrict__ dw3,
    float* __restrict__ M1p, float* __restrict__ Wc2, float* __restrict__ Wc3)
{
    int idx = blockIdx.x * 256 + threadIdx.x;
    if (idx < 9408) {                       // M1p [784][12]
        int m = idx / 12, j = idx % 12;
        float acc = 0.f;
        if (j < 9) {
            int oc = m / 49, r = m % 49, oy = r / 7, ox = r % 7;
            acc = (j == 8) ? db1[oc] : 0.f;
            for (int ky = 0; ky < 5; ++ky) {
                int ty = oy + ky - 2;
                if (ty < 0 || (ty & 1)) continue;
                int iy = ty >> 1; if (iy >= 4) continue;
                for (int kx = 0; kx < 5; ++kx) {
                    int tx = ox + kx - 2;
                    if (tx < 0 || (tx & 1)) continue;
                    int ix = tx >> 1; if (ix >= 4) continue;
                    for (int ic = 0; ic < 32; ++ic) {
                        float wv = dw1[((oc * 32 + ic) * 5 + ky) * 5 + kx];
                        int mi = ic * 16 + iy * 4 + ix;
                        acc += wv * ((j < 8) ? fc3w[mi * 8 + j] : fc3b[mi]);
                    }
                }
            }
        }
        M1p[idx] = acc;
    } else if (idx < 9408 + 3200) {         // Wc2 repack, dw2 [oc=8][ic=16][ky][kx]
        int iw = idx - 9408;
        int kx = iw % 5, t1 = iw / 5, ky = t1 % 5, t2 = t1 / 5, ic = t2 % 16, oc = t2 / 16;
        int cy = ky & 1, cx = kx & 1, dy = ky >> 1, dx = kx >> 1;
        int ny = cy ? 2 : 3, nx = cx ? 2 : 3, nt = ny * nx;
        const int off2[4] = {0, 1152, 1920, 2688};
        Wc2[off2[cy * 2 + cx] + (ic * 8 + oc) * nt + dy * nx + dx] = dw2[iw];
    } else if (idx < 9408 + 3200 + 200) {   // Wc3 repack
        int iw = idx - 12608;
        int kx = iw % 5, t1 = iw / 5, ky = t1 % 5, ic = t1 / 5;
        int cy = ky & 1, cx = kx & 1, dy = ky >> 1, dx = kx >> 1;
        int ny = cy ? 2 : 3, nx = cx ? 2 : 3, nt = ny * nx;
        const int off3[4] = {0, 72, 120, 168};
        Wc3[off3[cy * 2 + cx] + ic * nt + dy * nx + dx] = dw3[iw];
    }
}

// =====================================================================
// Encoder v2 (unchanged): branchless padded convs, LDS weights, parallel fc.
// =====================================================================
__global__ __launch_bounds__(256) void enc_kernel(
    const float* __restrict__ X, const float* __restrict__ eps,
    const float* __restrict__ w1, const float* __restrict__ b1,
    const float* __restrict__ w2, const float* __restrict__ b2,
    const float* __restrict__ w3, const float* __restrict__ b3,
    const float* __restrict__ fc1w, const float* __restrict__ fc1b,
    const float* __restrict__ fc2w, const float* __restrict__ fc2b,
    float* __restrict__ out, float* __restrict__ z0, float* __restrict__ klp)
{
    __shared__ float imgp[33][33];
    __shared__ float a1p[8][17][17];
    __shared__ float a2p[16][11][11];
    __shared__ float h[512];
    __shared__ float w1s[200];
    __shared__ float w2s[3200];
    __shared__ float w3s[12800];
    __shared__ float fcred[16];
    __shared__ float kl_s[8];
    int n = blockIdx.x, tid = threadIdx.x;

    for (int i = tid; i < 1089; i += 256) ((float*)imgp)[i] = 0.f;
    for (int i = tid; i < 2312; i += 256) ((float*)a1p)[i] = 0.f;
    for (int i = tid; i < 1936; i += 256) ((float*)a2p)[i] = 0.f;
    for (int i = tid; i < 50;   i += 256) ((float4*)w1s)[i] = ((const float4*)w1)[i];
    for (int i = tid; i < 800;  i += 256) ((float4*)w2s)[i] = ((const float4*)w2)[i];
    for (int i = tid; i < 3200; i += 256) ((float4*)w3s)[i] = ((const float4*)w3)[i];
    __syncthreads();

    const float* xi = X + (size_t)n * 39200;
    for (int i = tid; i < 784; i += 256) imgp[2 + i / 28][2 + i % 28] = xi[i];
    __syncthreads();

    for (int idx = tid; idx < 1568; idx += 256) {
        int oc = idx / 196, r = idx % 196, oy = r / 14, ox = r % 14;
        float acc = b1[oc];
        const float* wp = w1s + oc * 25;
        #pragma unroll
        for (int ky = 0; ky < 5; ++ky)
            #pragma unroll
            for (int kx = 0; kx < 5; ++kx)
                acc = fmaf(wp[ky * 5 + kx], imgp[2 * oy + ky][2 * ox + kx], acc);
        a1p[oc][2 + oy][2 + ox] = fmaxf(acc, 0.f);
    }
    __syncthreads();

    for (int idx = tid; idx < 784; idx += 256) {
        int oc = idx / 49, r = idx % 49, oy = r / 7, ox = r % 7;
        float acc = b2[oc];
        #pragma unroll 2
        for (int ic = 0; ic < 8; ++ic) {
            const float* wp = w2s + (oc * 8 + ic) * 25;
            #pragma unroll
            for (int ky = 0; ky < 5; ++ky)
                #pragma unroll
                for (int kx = 0; kx < 5; ++kx)
                    acc = fmaf(wp[ky * 5 + kx], a1p[ic][2 * oy + ky][2 * ox + kx], acc);
        }
        a2p[oc][2 + oy][2 + ox] = fmaxf(acc, 0.f);
    }
    __syncthreads();

    for (int idx = tid; idx < 512; idx += 256) {
        int oc = idx / 16, r = idx % 16, oy = r / 4, ox = r % 4;
        float acc = b3[oc];
        #pragma unroll 2
        for (int ic = 0; ic < 16; ++ic) {
            const float* wp = w3s + (oc * 16 + ic) * 25;
            #pragma unroll
            for (int ky = 0; ky < 5; ++ky)
                #pragma unroll
                for (int kx = 0; kx < 5; ++kx)
                    acc = fmaf(wp[ky * 5 + kx], a2p[ic][2 * oy + ky][2 * ox + kx], acc);
        }
        h[oc * 16 + r] = fmaxf(acc, 0.f);
    }
    __syncthreads();

    if (tid < 128) {
        int wv = tid >> 6, L = tid & 63, o = L >> 3, rr = L & 7;
        const float* fw = (wv ? fc2w : fc1w) + o * 512;
        float p = 0.f;
        #pragma unroll 8
        for (int j = 0; j < 64; ++j) {
            int k = rr + 8 * j;
            p = fmaf(fw[k], h[k], p);
        }
        p += __shfl_down(p, 4, 8);
        p += __shfl_down(p, 2, 8);
        p += __shfl_down(p, 1, 8);
        if (rr == 0) fcred[wv * 8 + o] = p;
    }
    __syncthreads();
    if (tid < 8) {
        float m = fc1b[tid] + fcred[tid];
        float lv = fc2b[tid] + fcred[8 + tid];
        float v = fmaxf(lv, 0.f) + log1pf(expf(-fabsf(lv)));
        float z = m + eps[n * 8 + tid] * v;
        out[QM_OFF + n * 8 + tid] = m;
        out[QV_OFF + n * 8 + tid] = v;
        z0[n * 8 + tid] = z;
        kl_s[tid] = -logf(v) + 0.5f * (v * v + m * m) - 0.5f;
    }
    __syncthreads();
    if (tid == 0) {
        float s = 0.f;
        for (int i = 0; i < 8; ++i) s += kl_s[i];
        klp[n] = s;
    }
}

// =====================================================================
// ODE v4 (unchanged): 4 waves per sample, k-split 25 per wave.
// =====================================================================
__device__ __forceinline__ float rl(float v, int lane) {
    return __uint_as_float(__builtin_amdgcn_readlane(__float_as_uint(v), lane));
}

__global__ __launch_bounds__(256, 1) void ode_kernel(
    const float* __restrict__ z0,
    const float* __restrict__ fw1, const float* __restrict__ fb1,
    const float* __restrict__ fw2, const float* __restrict__ fb2,
    const float* __restrict__ fw3, const float* __restrict__ fb3,
    float* __restrict__ ztg)
{
    __shared__ float part2[4][104];
    __shared__ float part3[4][8];
    int n = blockIdx.x, tid = threadIdx.x;
    int w = tid >> 6, L = tid & 63;
    int i3 = L & 7;
    bool act25 = (L < 25);
    int j1 = 25 * w + L;
    bool hiv = (L < 36);
    int jA = L, jB = L + 64;
    int k0 = 25 * w;

    float w1r[8];
    float b1A = 0.f, b2A = 0.f;
    if (act25) {
        b1A = fb1[j1];
        b2A = fb2[j1];
        #pragma unroll
        for (int k = 0; k < 8; ++k) w1r[k] = fw1[j1 * 8 + k];
    } else {
        #pragma unroll
        for (int k = 0; k < 8; ++k) w1r[k] = 0.f;
    }
    float w2x[25], w2y[25], w3r[25];
    #pragma unroll
    for (int kk = 0; kk < 25; ++kk) {
        w2x[kk] = fw2[jA * 100 + k0 + kk];
        w2y[kk] = hiv ? fw2[jB * 100 + k0 + kk] : 0.f;
        w3r[kk] = fw3[i3 * 100 + k0 + kk];
    }
    float b3r = fb3[i3];

    float zc = z0[n * 8 + i3];
    if (tid < 8) ztg[n * 400 + tid] = zc;
    float vu[8];
    #pragma unroll
    for (int i = 0; i < 8; ++i) vu[i] = rl(zc, i);

    #pragma unroll 1
    for (int t = 1; t < 50; ++t) {
        float zsum = 0.f;
        #pragma unroll 1
        for (int st = 0; st < 4; ++st) {
            float aA = 0.f;
            if (act25) {
                float a = b1A;
                #pragma unroll
                for (int k = 0; k < 8; ++k) a = fmaf(w1r[k], vu[k], a);
                aA = fmaxf(a, 0.f);
            }

            float ha[4] = {0.f, 0.f, 0.f, 0.f};
            float hb[4] = {0.f, 0.f, 0.f, 0.f};
            #pragma unroll
            for (int kk = 0; kk < 25; ++kk) {
                float s = rl(aA, kk);
                ha[kk & 3] = fmaf(w2x[kk], s, ha[kk & 3]);
                hb[kk & 3] = fmaf(w2y[kk], s, hb[kk & 3]);
            }
            part2[w][L] = (ha[0] + ha[1]) + (ha[2] + ha[3]);
            if (hiv) part2[w][64 + L] = (hb[0] + hb[1]) + (hb[2] + hb[3]);
            __syncthreads();

            float h2v = 0.f;
            if (act25) {
                float sA = (part2[0][j1] + part2[1][j1]) + (part2[2][j1] + part2[3][j1]);
                h2v = fmaxf(b2A + sA, 0.f);
            }

            float oa[4] = {0.f, 0.f, 0.f, 0.f};
            #pragma unroll
            for (int kk = 0; kk < 25; ++kk) {
                float s = rl(h2v, kk);
                oa[kk & 3] = fmaf(w3r[kk], s, oa[kk & 3]);
            }
            if (L < 8) part3[w][L] = (oa[0] + oa[1]) + (oa[2] + oa[3]);
            __syncthreads();

            float o = b3r + ((part3[0][i3] + part3[1][i3]) + (part3[2][i3] + part3[3][i3]));
            float cw = (st == 0 || st == 3) ? (DT / 6.f) : (DT / 3.f);
            zsum = fmaf(cw, o, zsum);
            float vn;
            if (st < 3) {
                float cin = (st == 2) ? DT : 0.5f * DT;
                vn = fmaf(cin, o, zc);
            } else {
                zc = zc + zsum;
                vn = zc;
                if (tid < 8) ztg[n * 400 + t * 8 + tid] = zc;
            }
            #pragma unroll
            for (int i = 0; i < 8; ++i) vu[i] = rl(vn, i);
        }
    }
}

// =====================================================================
// Decoder v7: bf16 LDS activation tiles (29.9 KB -> 5 blocks/CU).
// fp32 weights + fp32 accumulate; structure identical to v5.
// =====================================================================
__global__ __launch_bounds__(256, 5) void dec_kernel(
    const float* __restrict__ M1p, const float* __restrict__ zt,
    const float* __restrict__ Wc2, const float* __restrict__ db2,
    const float* __restrict__ Wc3, const float* __restrict__ db3,
    const float* __restrict__ X, float* __restrict__ xrec,
    float* __restrict__ lhp)
{
    __shared__ __align__(16) unsigned short y1h[4][16][9][10];   // bf16, 11520 B
    __shared__ __align__(16) unsigned short y2h[4][8][16][17];   // bf16, 17408 B
    __shared__ float red[256];
    int blk = blockIdx.x, tid = threadIdx.x;
    int wv = tid >> 6, L = tid & 63;

    {
        uint4 z4 = uint4{0u, 0u, 0u, 0u};
        for (int i = tid; i < 720;  i += 256) ((uint4*)y1h)[i] = z4;
        for (int i = tid; i < 1088; i += 256) ((uint4*)y2h)[i] = z4;
    }
    __syncthreads();

    // phase 0: y1 = relu(M1 @ z + b) for 4 samples
    {
        float zr[4][8];
        const float* zp = zt + (size_t)blk * 32;
        #pragma unroll
        for (int s = 0; s < 4; ++s)
            #pragma unroll
            for (int jj = 0; jj < 8; ++jj) zr[s][jj] = zp[s * 8 + jj];
        for (int m = tid; m < 784; m += 256) {
            const float4* row = (const float4*)(M1p + m * 12);
            float4 r0 = row[0], r1 = row[1], r2 = row[2];
            int oc = m / 49, r = m % 49, oy = r / 7, ox = r % 7;
            #pragma unroll
            for (int s = 0; s < 4; ++s) {
                float acc = r2.x;
                acc += r0.x * zr[s][0] + r0.y * zr[s][1] + r0.z * zr[s][2] + r0.w * zr[s][3]
                     + r1.x * zr[s][4] + r1.y * zr[s][5] + r1.z * zr[s][6] + r1.w * zr[s][7];
                y1h[s][oc][1 + oy][1 + ox] = f2bf(fmaxf(acc, 0.f));
            }
        }
    }
    __syncthreads();

    // phase 1: convT2 fused 4-class 2x2 tiles. wave -> sample, lane -> (m,n).
    if (L < 49) {
        int s = wv, m = L / 7, n = L % 7;
        float acc[4][8];
        #pragma unroll
        for (int oc = 0; oc < 8; ++oc) {
            float b = db2[oc];
            acc[0][oc] = b; acc[1][oc] = b; acc[2][oc] = b; acc[3][oc] = b;
        }
        const float* w00 = Wc2;
        const float* w01 = Wc2 + 1152;
        const float* w10 = Wc2 + 1920;
        const float* w11 = Wc2 + 2688;
        #pragma unroll 2
        for (int ic = 0; ic < 16; ++ic) {
            float yv[3][3];
            #pragma unroll
            for (int ry = 0; ry < 3; ++ry)
                #pragma unroll
                for (int rx = 0; rx < 3; ++rx)
                    yv[ry][rx] = bf2f(y1h[s][ic][m + ry][n + rx]);
            #pragma unroll
            for (int oc = 0; oc < 8; ++oc) {
                const float* p00 = w00 + (ic * 8 + oc) * 9;
                const float* p01 = w01 + (ic * 8 + oc) * 6;
                const float* p10 = w10 + (ic * 8 + oc) * 6;
                const float* p11 = w11 + (ic * 8 + oc) * 4;
                #pragma unroll
                for (int dy = 0; dy < 3; ++dy)
                    #pragma unroll
                    for (int dx = 0; dx < 3; ++dx)
                        acc[0][oc] = fmaf(p00[dy * 3 + dx], yv[dy][dx], acc[0][oc]);
                #pragma unroll
                for (int dy = 0; dy < 3; ++dy)
                    #pragma unroll
                    for (int dx = 0; dx < 2; ++dx)
                        acc[1][oc] = fmaf(p01[dy * 2 + dx], yv[dy][dx + 1], acc[1][oc]);
                #pragma unroll
                for (int dy = 0; dy < 2; ++dy)
                    #pragma unroll
                    for (int dx = 0; dx < 3; ++dx)
                        acc[2][oc] = fmaf(p10[dy * 3 + dx], yv[dy + 1][dx], acc[2][oc]);
                #pragma unroll
                for (int dy = 0; dy < 2; ++dy)
                    #pragma unroll
                    for (int dx = 0; dx < 2; ++dx)
                        acc[3][oc] = fmaf(p11[dy * 2 + dx], yv[dy + 1][dx + 1], acc[3][oc]);
            }
        }
        #pragma unroll
        for (int oc = 0; oc < 8; ++oc) {
            y2h[s][oc][1 + 2 * m][1 + 2 * n]         = f2bf(fmaxf(acc[0][oc], 0.f));
            y2h[s][oc][1 + 2 * m][1 + 2 * n + 1]     = f2bf(fmaxf(acc[1][oc], 0.f));
            y2h[s][oc][1 + 2 * m + 1][1 + 2 * n]     = f2bf(fmaxf(acc[2][oc], 0.f));
            y2h[s][oc][1 + 2 * m + 1][1 + 2 * n + 1] = f2bf(fmaxf(acc[3][oc], 0.f));
        }
    }
    __syncthreads();

    // phase 2: convT3 fused 4-class 2x2 tiles + sigmoid + lhood
    float part = 0.f;
    {
        float b3v = db3[0];
        const float* q00 = Wc3;
        const float* q01 = Wc3 + 72;
        const float* q10 = Wc3 + 120;
        const float* q11 = Wc3 + 168;
        #pragma unroll 1
        for (int ch = 0; ch < 4; ++ch) {
            int g = ch * 256 + tid;
            if (g < 784) {
                int s2 = g / 196, r2 = g % 196, m = r2 / 14, n = r2 % 14;
                float o00 = b3v, o01 = b3v, o10 = b3v, o11 = b3v;
                #pragma unroll 2
                for (int ic = 0; ic < 8; ++ic) {
                    float yv[3][3];
                    #pragma unroll
                    for (int ry = 0; ry < 3; ++ry)
                        #pragma unroll
                        for (int rx = 0; rx < 3; ++rx)
                            yv[ry][rx] = bf2f(y2h[s2][ic][m + ry][n + rx]);
                    #pragma unroll
                    for (int dy = 0; dy < 3; ++dy)
                        #pragma unroll
                        for (int dx = 0; dx < 3; ++dx)
                            o00 = fmaf(q00[ic * 9 + dy * 3 + dx], yv[dy][dx], o00);
                    #pragma unroll
                    for (int dy = 0; dy < 3; ++dy)
                        #pragma unroll
                        for (int dx = 0; dx < 2; ++dx)
                            o01 = fmaf(q01[ic * 6 + dy * 2 + dx], yv[dy][dx + 1], o01);
                    #pragma unroll
                    for (int dy = 0; dy < 2; ++dy)
                        #pragma unroll
                        for (int dx = 0; dx < 3; ++dx)
                            o10 = fmaf(q10[ic * 6 + dy * 3 + dx], yv[dy + 1][dx], o10);
                    #pragma unroll
                    for (int dy = 0; dy < 2; ++dy)
                        #pragma unroll
                        for (int dx = 0; dx < 2; ++dx)
                            o11 = fmaf(q11[ic * 4 + dy * 2 + dx], yv[dy + 1][dx + 1], o11);
                }
                float p00s = 1.f / (1.f + __expf(-o00));
                float p01s = 1.f / (1.f + __expf(-o01));
                float p10s = 1.f / (1.f + __expf(-o10));
                float p11s = 1.f / (1.f + __expf(-o11));
                size_t base = (size_t)blk * 3136 + s2 * 784 + 2 * m * 28 + 2 * n;
                *(float2*)(xrec + base)      = float2{p00s, p01s};
                *(float2*)(xrec + base + 28) = float2{p10s, p11s};
                float2 x0 = *(const float2*)(X + base);
                float2 x1 = *(const float2*)(X + base + 28);
                part += __logf(EPSL + p00s) * x0.x + __logf(EPSL + 1.f - p00s) * (1.f - x0.x);
                part += __logf(EPSL + p01s) * x0.y + __logf(EPSL + 1.f - p01s) * (1.f - x0.y);
                part += __logf(EPSL + p10s) * x1.x + __logf(EPSL + 1.f - p10s) * (1.f - x1.x);
                part += __logf(EPSL + p11s) * x1.y + __logf(EPSL + 1.f - p11s) * (1.f - x1.y);
            }
        }
    }
    red[tid] = part;
    __syncthreads();
    for (int st = 128; st > 0; st >>= 1) {
        if (tid < st) red[tid] += red[tid + st];
        __syncthreads();
    }
    if (tid == 0) lhp[blk] = red[0];
}

// =====================================================================
// Finalize
// =====================================================================
__global__ __launch_bounds__(256) void fin_kernel(
    const float* __restrict__ lhp, const float* __restrict__ klp,
    float* __restrict__ out)
{
    __shared__ double red[256];
    int tid = threadIdx.x;
    double s = 0.0;
    for (int i = tid; i < 3200; i += 256) s += (double)lhp[i];
    red[tid] = s;
    __syncthreads();
    for (int st = 128; st > 0; st >>= 1) {
        if (tid < st) red[tid] += red[tid + st];
        __syncthreads();
    }
    double lh = red[0];
    __syncthreads();
    red[tid] = (double)klp[tid];
    __syncthreads();
    for (int st = 128; st > 0; st >>= 1) {
        if (tid < st) red[tid] += red[tid + st];
        __syncthreads();
    }
    if (tid == 0) {
        out[LH_OFF] = (float)(lh / 256.0);
        out[KL_OFF] = (float)(red[0] / 2048.0);
    }
}

extern "C" void kernel_launch(void* const* d_in, const int* in_sizes, int n_in,
                              void* d_out, int out_size, void* d_ws, size_t ws_size,
                              hipStream_t stream) {
    const float* X     = (const float*)d_in[0];
    const float* eps   = (const float*)d_in[1];
    const float* ew1   = (const float*)d_in[2];
    const float* eb1   = (const float*)d_in[3];
    const float* ew2   = (const float*)d_in[4];
    const float* eb2   = (const float*)d_in[5];
    const float* ew3   = (const float*)d_in[6];
    const float* eb3   = (const float*)d_in[7];
    const float* fc1w  = (const float*)d_in[8];
    const float* fc1b  = (const float*)d_in[9];
    const float* fc2w  = (const float*)d_in[10];
    const float* fc2b  = (const float*)d_in[11];
    const float* fw1   = (const float*)d_in[12];
    const float* fb1   = (const float*)d_in[13];
    const float* fw2   = (const float*)d_in[14];
    const float* fb2   = (const float*)d_in[15];
    const float* fw3   = (const float*)d_in[16];
    const float* fb3   = (const float*)d_in[17];
    const float* fc3w  = (const float*)d_in[18];
    const float* fc3b  = (const float*)d_in[19];
    const float* dw1   = (const float*)d_in[20];
    const float* db1   = (const float*)d_in[21];
    const float* dw2   = (const float*)d_in[22];
    const float* db2   = (const float*)d_in[23];
    const float* dw3   = (const float*)d_in[24];
    const float* db3   = (const float*)d_in[25];

    float* out = (float*)d_out;
    char* ws = (char*)d_ws;
    float* lhp = (float*)ws;
    float* klp = (float*)(ws + 12800);
    float* z0  = (float*)(ws + 13824);
    float* M1p = (float*)(ws + 22016);
    float* Wc2 = (float*)(ws + 59648);
    float* Wc3 = (float*)(ws + 72448);

    prep_kernel<<<51, 256, 0, stream>>>(fc3w, fc3b, dw1, db1, dw2, dw3, M1p, Wc2, Wc3);
    enc_kernel<<<256, 256, 0, stream>>>(X, eps, ew1, eb1, ew2, eb2, ew3, eb3,
                                        fc1w, fc1b, fc2w, fc2b, out, z0, klp);
    ode_kernel<<<256, 256, 0, stream>>>(z0, fw1, fb1, fw2, fb2, fw3, fb3, out + ZT_OFF);
    dec_kernel<<<3200, 256, 0, stream>>>(M1p, out + ZT_OFF, Wc2, db2, Wc3, db3,
                                         X, out + XREC_OFF, lhp);
    fin_kernel<<<1, 256, 0, stream>>>(lhp, klp, out);
}